// Round 11
// baseline (736.458 us; speedup 1.0000x reference)
//
#include <hip/hip_runtime.h>

#define NEG_SLOPE 0.2f

typedef __attribute__((ext_vector_type(8))) short short8;
typedef __attribute__((ext_vector_type(8))) unsigned short ushort8;
typedef __attribute__((ext_vector_type(4))) float f32x4;

__device__ __forceinline__ unsigned short f2bf(float f) {
    unsigned int u = __float_as_uint(f);
    u += 0x7fff + ((u >> 16) & 1);     // round-to-nearest-even
    return (unsigned short)(u >> 16);
}
__device__ __forceinline__ float bf2f(unsigned short s) {
    return __uint_as_float(((unsigned int)s) << 16);
}

// async global->LDS, 16B per lane; lds base must be wave-uniform
__device__ __forceinline__ void gll16(const void* g, void* l) {
    __builtin_amdgcn_global_load_lds(
        (const __attribute__((address_space(1))) void*)g,
        (__attribute__((address_space(3))) void*)l, 16, 0, 0);
}

// ---------------- converters ----------------
__global__ void conv_k(const float* __restrict__ in, unsigned short* __restrict__ out, long n)
{
    long i = ((long)blockIdx.x * blockDim.x + threadIdx.x) * 4;
    if (i >= n) return;
    float4 f = *(const float4*)&in[i];
    ushort4 o; o.x = f2bf(f.x); o.y = f2bf(f.y); o.z = f2bf(f.z); o.w = f2bf(f.w);
    *(ushort4*)&out[i] = o;
}

// all 15 weights in one launch; supports column-offset packing into wider dst:
// Wc[((k>>3)*MoD + off + m)*8 + (k&7)] = bf16(W[k*MoS + m])
struct WPack {
    const float* W[15];
    unsigned short* Wc[15];
    int K[15];
    int MoS[15];
    int MoD[15];
    int off[15];
};
__global__ void convW_all(WPack p)
{
    int wi = blockIdx.y;
    int i = blockIdx.x * blockDim.x + threadIdx.x;
    int K = p.K[wi], MoS = p.MoS[wi];
    if (i >= K * MoS) return;
    int k = i / MoS, m = i % MoS;
    p.Wc[wi][((long)(k >> 3) * p.MoD[wi] + p.off[wi] + m) * 8 + (k & 7)] = f2bf(p.W[wi][i]);
}

// XCD-grouping remap (bijective with pad): consecutive work items share an XCD L2.
__device__ __forceinline__ int xcd_work(int TOT) {
    int L = blockIdx.x;
    int per = (TOT + 7) >> 3;
    int wk = (L & 7) * per + (L >> 3);
    return (wk < TOT) ? wk : -1;
}

// ================= bf16 MFMA GEMM: BM=64, BK=64, 4 waves (2x2) =================
// BN=128: wave tile 32x64 (2x4 frags). BN=64: wave tile 32x32 (2x2 frags).
// MODE 0: outF/outB = acc+bias (either may be null)
// MODE 3: o = (1-z)*hin + z*tanh(acc+bias), z/hin bf16; outB   (GRU finish, L1/L2)
// MODE 4: split projection: col<Mo/2 -> outF/outB = acc+bias[col] ([rows,Mo/2])
//         col>=Mo/2 -> outB2 = bf16(acc)                         ([rows,Mo/2])
// MODE 5: o = (1-Zf)*HinF + Zf*tanh(acc+bias); outF fp32        (GRU finish, L3)
template<int BN, int MODE>
__global__ __launch_bounds__(256) void gemm_t(
    const unsigned short* __restrict__ U, int K1,
    const unsigned short* __restrict__ V, int K2,
    const unsigned short* __restrict__ Wc, const float* __restrict__ bias,
    float* __restrict__ outF, unsigned short* __restrict__ outB,
    unsigned short* __restrict__ outB2,
    const unsigned short* __restrict__ HinB, const unsigned short* __restrict__ Zb,
    const float* __restrict__ HinF, const float* __restrict__ Zf,
    int rows, int Mo)
{
    constexpr int NIF = BN / 32;       // frags per wave in N (WC=2)
    __shared__ __align__(16) unsigned short As[8][64][8];    // 8KB
    __shared__ __align__(16) unsigned short Bs[8][BN][8];    // 16KB / 8KB
    const int CB = Mo / BN;
    const int RB = (rows + 63) >> 6;
    int wk = xcd_work(CB * RB);
    if (wk < 0) return;
    const int col0 = (wk % CB) * BN;
    const int row0 = (wk / CB) * 64;
    const int K = K1 + K2;
    const int tid = threadIdx.x;
    const int l = tid & 63, w = tid >> 6;
    const int lm = l & 15, lg = l >> 4;
    const int wrow = (w >> 1) * 32;
    const int wcol = (w & 1) * (BN / 2);
    f32x4 acc[2][NIF] = {};

    for (int k0 = 0; k0 < K; k0 += 64) {
#pragma unroll
        for (int i = 0; i < 2; ++i) {
            int c = i * 256 + tid;
            int m = c & 63, g = c >> 6;           // g wave-uniform
            int row = row0 + m; if (row >= rows) row = rows - 1;
            int k = k0 + g * 8;
            const unsigned short* sp = (k < K1) ? U + (long)row * K1 + k
                                                : V + (long)row * K2 + (k - K1);
            gll16(sp, &As[0][0][0] + ((i * 256 + w * 64) << 3));
        }
#pragma unroll
        for (int j = 0; j < NIF; ++j) {
            int c = j * 256 + tid;
            int n = c & (BN - 1), g = c / BN;     // g wave-uniform
            gll16(Wc + ((long)((k0 >> 3) + g) * Mo + (col0 + n)) * 8,
                  &Bs[0][0][0] + ((j * 256 + w * 64) << 3));
        }
        __syncthreads();
#pragma unroll
        for (int kk = 0; kk < 2; ++kk) {
            short8 a[2], b[NIF];
#pragma unroll
            for (int mi = 0; mi < 2; ++mi)
                a[mi] = *(const short8*)&As[kk * 4 + lg][wrow + mi * 16 + lm][0];
#pragma unroll
            for (int ni = 0; ni < NIF; ++ni)
                b[ni] = *(const short8*)&Bs[kk * 4 + lg][wcol + ni * 16 + lm][0];
#pragma unroll
            for (int mi = 0; mi < 2; ++mi)
#pragma unroll
                for (int ni = 0; ni < NIF; ++ni)
                    acc[mi][ni] = __builtin_amdgcn_mfma_f32_16x16x32_bf16(a[mi], b[ni], acc[mi][ni], 0, 0, 0);
        }
        __syncthreads();
    }

    const int halfMo = Mo >> 1;
#pragma unroll
    for (int mi = 0; mi < 2; ++mi) {
        int rbase = row0 + wrow + mi * 16 + lg * 4;
#pragma unroll
        for (int r = 0; r < 4; ++r) {
            int row = rbase + r;
            if (row >= rows) continue;
#pragma unroll
            for (int ni = 0; ni < NIF; ++ni) {
                int col = col0 + wcol + ni * 16 + lm;
                float v = acc[mi][ni][r];
                if (MODE == 0) {
                    v += (bias ? bias[col] : 0.f);
                    long idx = (long)row * Mo + col;
                    if (outF) outF[idx] = v;
                    if (outB) outB[idx] = f2bf(v);
                } else if (MODE == 3) {
                    v += bias[col];
                    long idx = (long)row * Mo + col;
                    float z = bf2f(Zb[idx]);
                    float o = (1.f - z) * bf2f(HinB[idx]) + z * tanhf(v);
                    outB[idx] = f2bf(o);
                } else if (MODE == 5) {
                    v += bias[col];
                    long idx = (long)row * Mo + col;
                    float z = Zf[idx];
                    float o = (1.f - z) * HinF[idx] + z * tanhf(v);
                    outF[idx] = o;
                } else {  // MODE 4
                    if (col < halfMo) {
                        v += bias[col];
                        long idx = (long)row * halfMo + col;
                        if (outF) outF[idx] = v;
                        outB[idx] = f2bf(v);
                    } else {
                        outB2[(long)row * halfMo + (col - halfMo)] = f2bf(v);
                    }
                }
            }
        }
    }
}

// ================= fused r+z dual-B GEMM: BM=64, BN=64, shared A =================
// FP=0: hin/z in bf16 (L1/L2);  FP=1: hin/z in fp32 (L3)
//   RHb = bf16( sigmoid(acc_r + br) * hin ),  Zout = sigmoid(acc_z + bz)
template<int FP>
__global__ __launch_bounds__(256) void gemm_rz(
    const unsigned short* __restrict__ U, int K1,
    const unsigned short* __restrict__ V, int K2,
    const unsigned short* __restrict__ Wrc, const unsigned short* __restrict__ Wzc,
    const float* __restrict__ br, const float* __restrict__ bz,
    const unsigned short* __restrict__ HinB, const float* __restrict__ HinF,
    unsigned short* __restrict__ RHb,
    unsigned short* __restrict__ ZoutB, float* __restrict__ ZoutF,
    int rows, int Mo)
{
    __shared__ __align__(16) unsigned short As[8][64][8];   // 8KB
    __shared__ __align__(16) unsigned short Br[8][64][8];   // 8KB
    __shared__ __align__(16) unsigned short Bz[8][64][8];   // 8KB
    const int CB = Mo >> 6;
    const int RB = (rows + 63) >> 6;
    int wk = xcd_work(CB * RB);
    if (wk < 0) return;
    const int col0 = (wk % CB) * 64;
    const int row0 = (wk / CB) * 64;
    const int K = K1 + K2;
    const int tid = threadIdx.x;
    const int l = tid & 63, w = tid >> 6;
    const int lm = l & 15, lg = l >> 4;
    const int wrow = (w >> 1) * 32;
    const int wcol = (w & 1) * 32;
    f32x4 accr[2][2] = {}, accz[2][2] = {};

    for (int k0 = 0; k0 < K; k0 += 64) {
#pragma unroll
        for (int i = 0; i < 2; ++i) {
            int c = i * 256 + tid;
            int m = c & 63, g = c >> 6;
            int row = row0 + m; if (row >= rows) row = rows - 1;
            int k = k0 + g * 8;
            const unsigned short* sp = (k < K1) ? U + (long)row * K1 + k
                                                : V + (long)row * K2 + (k - K1);
            gll16(sp, &As[0][0][0] + ((i * 256 + w * 64) << 3));
        }
#pragma unroll
        for (int j = 0; j < 2; ++j) {
            int c = j * 256 + tid;
            int n = c & 63, g = c >> 6;
            long base = ((long)((k0 >> 3) + g) * Mo + (col0 + n)) * 8;
            gll16(Wrc + base, &Br[0][0][0] + ((j * 256 + w * 64) << 3));
            gll16(Wzc + base, &Bz[0][0][0] + ((j * 256 + w * 64) << 3));
        }
        __syncthreads();
#pragma unroll
        for (int kk = 0; kk < 2; ++kk) {
            short8 a[2], brv[2], bzv[2];
#pragma unroll
            for (int mi = 0; mi < 2; ++mi)
                a[mi] = *(const short8*)&As[kk * 4 + lg][wrow + mi * 16 + lm][0];
#pragma unroll
            for (int ni = 0; ni < 2; ++ni) {
                brv[ni] = *(const short8*)&Br[kk * 4 + lg][wcol + ni * 16 + lm][0];
                bzv[ni] = *(const short8*)&Bz[kk * 4 + lg][wcol + ni * 16 + lm][0];
            }
#pragma unroll
            for (int mi = 0; mi < 2; ++mi)
#pragma unroll
                for (int ni = 0; ni < 2; ++ni) {
                    accr[mi][ni] = __builtin_amdgcn_mfma_f32_16x16x32_bf16(a[mi], brv[ni], accr[mi][ni], 0, 0, 0);
                    accz[mi][ni] = __builtin_amdgcn_mfma_f32_16x16x32_bf16(a[mi], bzv[ni], accz[mi][ni], 0, 0, 0);
                }
        }
        __syncthreads();
    }

#pragma unroll
    for (int mi = 0; mi < 2; ++mi) {
        int rbase = row0 + wrow + mi * 16 + lg * 4;
#pragma unroll
        for (int r = 0; r < 4; ++r) {
            int row = rbase + r;
            if (row >= rows) continue;
#pragma unroll
            for (int ni = 0; ni < 2; ++ni) {
                int col = col0 + wcol + ni * 16 + lm;
                long idx = (long)row * Mo + col;
                float rv = 1.f / (1.f + __expf(-(accr[mi][ni][r] + br[col])));
                float zv = 1.f / (1.f + __expf(-(accz[mi][ni][r] + bz[col])));
                float hin = FP ? HinF[idx] : bf2f(HinB[idx]);
                RHb[idx] = f2bf(rv * hin);
                if (FP) ZoutF[idx] = zv;
                else    ZoutB[idx] = f2bf(zv);
            }
        }
    }
}

// ---------------- alpha (bf16 input) ----------------
__global__ void alpha_b(const unsigned short* __restrict__ XPb,
                        const float* __restrict__ a_s, const float* __restrict__ a_d,
                        float* __restrict__ AS, float* __restrict__ AD,
                        int Nn, int H, int C)
{
    int i = blockIdx.x * blockDim.x + threadIdx.x;
    if (i >= Nn * H) return;
    int n = i / H, h = i % H;
    const unsigned short* xp = &XPb[(long)n * H * C + (long)h * C];
    float ss = 0.f, sd = 0.f;
    for (int c = 0; c < C; ++c) {
        float v = bf2f(xp[c]);
        ss += v * a_s[h * C + c];
        sd += v * a_d[h * C + c];
    }
    AS[i] = ss; AD[i] = sd;
}

// ---------------- CSR build ----------------
__global__ void count_k(const int* __restrict__ dst, int E, int* __restrict__ cnt)
{
    int e = blockIdx.x * blockDim.x + threadIdx.x;
    if (e < E) atomicAdd(&cnt[dst[e]], 1);
}

__global__ __launch_bounds__(1024) void scan_k(const int* __restrict__ cnt, int Nn,
                                               int* __restrict__ off)
{
    __shared__ int part[1024];
    int tid = threadIdx.x;
    int chunk = (Nn + 1023) / 1024;
    int b = tid * chunk;
    int e = b + chunk; if (e > Nn) e = Nn; if (b > Nn) b = Nn;
    int s = 0;
    for (int i = b; i < e; ++i) s += cnt[i];
    part[tid] = s;
    __syncthreads();
    for (int d = 1; d < 1024; d <<= 1) {
        int v = (tid >= d) ? part[tid - d] : 0;
        __syncthreads();
        part[tid] += v;
        __syncthreads();
    }
    int run = tid ? part[tid - 1] : 0;
    for (int i = b; i < e; ++i) { off[i] = run; run += cnt[i]; }
    if (tid == 1023) off[Nn] = part[1023];
}

__global__ void scatter_k(const int* __restrict__ src, const int* __restrict__ dst, int E,
                          const int* __restrict__ off, int* __restrict__ cur,
                          int* __restrict__ csr_src)
{
    int e = blockIdx.x * blockDim.x + threadIdx.x;
    if (e < E) {
        int d = dst[e];
        int p = atomicAdd(&cur[d], 1);
        csr_src[off[d] + p] = src[e];
    }
}

// ---------------- feature-sliced bf16 GAT gather ----------------
// slice = blockIdx % SLICES (32 features each). Under round-robin block->XCD
// dispatch, same-slice blocks share an XCD -> per-XCD working set
// Nn * 64B = 3.2MB, L2-resident. 4 lanes per node (8 feats each), 16 nodes/wave.
// VALU-identical to unsliced version; summation order per feature unchanged.
template<int SLICES>
__global__ void gat_gather_s(const int* __restrict__ off, const int* __restrict__ csr_src,
                             const unsigned short* __restrict__ XPb,
                             const float* __restrict__ AS, const float* __restrict__ AD,
                             const float* __restrict__ bias,
                             unsigned short* __restrict__ Gout,
                             int Nn, int H, int C, int do_elu)
{
    const int D = SLICES * 32;
    const int slice = blockIdx.x % SLICES;
    const int nodeblk = blockIdx.x / SLICES;
    const int tid = threadIdx.x;
    const int waveid = tid >> 6, lane = tid & 63;
    const long n = ((long)nodeblk * 4 + waveid) * 16 + (lane >> 2);
    if (n >= Nn) return;
    const int j = (slice * 4 + (lane & 3)) * 8;
    const int h = j / C;
    float ad = AD[n * H + h];
    float v = AS[n * H + h] + ad;
    v = v > 0.f ? v : NEG_SLOPE * v;
    float w = __expf(v);
    float den = w;
    float acc[8];
    {
        ushort8 xv = *(const ushort8*)&XPb[(long)n * D + j];
#pragma unroll
        for (int q = 0; q < 8; ++q) acc[q] = w * bf2f(xv[q]);
    }
    int b0 = off[n], b1 = off[n + 1];
    int i = b0;
    for (; i + 4 <= b1; i += 4) {
        int s0 = csr_src[i + 0];
        int s1 = csr_src[i + 1];
        int s2 = csr_src[i + 2];
        int s3 = csr_src[i + 3];
        float v0 = AS[s0 * H + h] + ad;
        float v1 = AS[s1 * H + h] + ad;
        float v2 = AS[s2 * H + h] + ad;
        float v3 = AS[s3 * H + h] + ad;
        v0 = v0 > 0.f ? v0 : NEG_SLOPE * v0;
        v1 = v1 > 0.f ? v1 : NEG_SLOPE * v1;
        v2 = v2 > 0.f ? v2 : NEG_SLOPE * v2;
        v3 = v3 > 0.f ? v3 : NEG_SLOPE * v3;
        float w0 = __expf(v0), w1 = __expf(v1), w2 = __expf(v2), w3 = __expf(v3);
        den += (w0 + w1) + (w2 + w3);
        ushort8 x0 = *(const ushort8*)&XPb[(long)s0 * D + j];
        ushort8 x1 = *(const ushort8*)&XPb[(long)s1 * D + j];
        ushort8 x2 = *(const ushort8*)&XPb[(long)s2 * D + j];
        ushort8 x3 = *(const ushort8*)&XPb[(long)s3 * D + j];
#pragma unroll
        for (int q = 0; q < 8; ++q)
            acc[q] += w0 * bf2f(x0[q]) + w1 * bf2f(x1[q]) + w2 * bf2f(x2[q]) + w3 * bf2f(x3[q]);
    }
    for (; i < b1; ++i) {
        int s = csr_src[i];
        v = AS[s * H + h] + ad;
        v = v > 0.f ? v : NEG_SLOPE * v;
        w = __expf(v);
        den += w;
        ushort8 xv = *(const ushort8*)&XPb[(long)s * D + j];
#pragma unroll
        for (int q = 0; q < 8; ++q) acc[q] += w * bf2f(xv[q]);
    }
    float inv = 1.f / (den + 1e-16f);
    ushort8 ov;
#pragma unroll
    for (int q = 0; q < 8; ++q) {
        float o = acc[q] * inv + bias[j + q];
        if (do_elu) o = o > 0.f ? o : expm1f(o);
        ov[q] = f2bf(o);
    }
    *(ushort8*)&Gout[(long)n * D + j] = ov;
}

static inline int pad8(int t) { return ((t + 7) / 8) * 8; }
static inline int gblocks(int rows, int Mo, int BN) {
    return pad8((Mo / BN) * ((rows + 63) >> 6));
}

static inline void launch_gather(const int* ioff, const int* csr,
                                 const unsigned short* xp, const float* AS, const float* AD,
                                 const float* bias, unsigned short* gout,
                                 int Nn, int H, int C, int elu, hipStream_t stream)
{
    int D = H * C;
    int slices = D / 32;
    int nodeblks = (Nn + 63) / 64;
    int blocks = nodeblks * slices;
    if (slices == 8)
        gat_gather_s<8><<<blocks, 256, 0, stream>>>(ioff, csr, xp, AS, AD, bias, gout, Nn, H, C, elu);
    else if (slices == 4)
        gat_gather_s<4><<<blocks, 256, 0, stream>>>(ioff, csr, xp, AS, AD, bias, gout, Nn, H, C, elu);
    else
        gat_gather_s<2><<<blocks, 256, 0, stream>>>(ioff, csr, xp, AS, AD, bias, gout, Nn, H, C, elu);
}

extern "C" void kernel_launch(void* const* d_in, const int* in_sizes, int n_in,
                              void* d_out, int out_size, void* d_ws, size_t ws_size,
                              hipStream_t stream)
{
    const float* x    = (const float*)d_in[0];
    const int*   ei   = (const int*)  d_in[1];
    const float* W_tr = (const float*)d_in[2];
    const float* b_tr = (const float*)d_in[3];
    const float* W1   = (const float*)d_in[4];
    const float* as1  = (const float*)d_in[5];
    const float* ad1  = (const float*)d_in[6];
    const float* b1   = (const float*)d_in[7];
    const float* Wr1  = (const float*)d_in[8];
    const float* br1  = (const float*)d_in[9];
    const float* Wz1  = (const float*)d_in[10];
    const float* bz1  = (const float*)d_in[11];
    const float* Wh1  = (const float*)d_in[12];
    const float* bh1  = (const float*)d_in[13];
    const float* Wp2  = (const float*)d_in[14];
    const float* bp2  = (const float*)d_in[15];
    const float* W2   = (const float*)d_in[16];
    const float* as2  = (const float*)d_in[17];
    const float* ad2  = (const float*)d_in[18];
    const float* b2   = (const float*)d_in[19];
    const float* Wr2  = (const float*)d_in[20];
    const float* br2  = (const float*)d_in[21];
    const float* Wz2  = (const float*)d_in[22];
    const float* bz2  = (const float*)d_in[23];
    const float* Wh2  = (const float*)d_in[24];
    const float* bh2  = (const float*)d_in[25];
    const float* Wp3  = (const float*)d_in[26];
    const float* bp3  = (const float*)d_in[27];
    const float* W3   = (const float*)d_in[28];
    const float* as3  = (const float*)d_in[29];
    const float* ad3  = (const float*)d_in[30];
    const float* b3   = (const float*)d_in[31];
    const float* Wr3  = (const float*)d_in[32];
    const float* br3  = (const float*)d_in[33];
    const float* Wz3  = (const float*)d_in[34];
    const float* bz3  = (const float*)d_in[35];
    const float* Wh3  = (const float*)d_in[36];
    const float* bh3  = (const float*)d_in[37];

    const int Nn = in_sizes[0] / 128;   // 50000
    const int E  = in_sizes[1] / 2;     // 800000
    const int* srcp = ei;
    const int* dstp = ei + E;

    // ---------------- workspace layout (bf16-state) ----------------
    float* AS  = (float*)d_ws;                          // [N,8]
    float* AD  = AS + (size_t)Nn * 8;                   // [N,8]
    float* H3f = AD + (size_t)Nn * 8;                   // [N,64] fp32 (L3 h_in)
    float* Z3f = H3f + (size_t)Nn * 64;                 // [N,64] fp32 (L3 z)
    unsigned short* X0b  = (unsigned short*)(Z3f + (size_t)Nn * 64); // [N,256]
    unsigned short* XPb  = X0b + (size_t)Nn * 256;      // [N,256]
    unsigned short* Gb   = XPb + (size_t)Nn * 256;      // [N,256]
    unsigned short* RHb  = Gb  + (size_t)Nn * 256;      // [N,256]
    unsigned short* HINb = RHb + (size_t)Nn * 256;      // [N,128]
    unsigned short* Zb   = HINb + (size_t)Nn * 128;     // [N,256]
    unsigned short* wpool = Zb + (size_t)Nn * 256;
    unsigned short* Wtrc   = wpool;                     // 128*256
    unsigned short* W1c    = Wtrc   + 128 * 256;        // 256*256
    unsigned short* Wr1c   = W1c    + 256 * 256;        // 512*256
    unsigned short* Wz1c   = Wr1c   + 512 * 256;
    unsigned short* Wh1c   = Wz1c   + 512 * 256;
    unsigned short* Wp2W2c = Wh1c   + 512 * 256;        // 256*256 combined
    unsigned short* Wr2c   = Wp2W2c + 256 * 256;        // 256*128
    unsigned short* Wz2c   = Wr2c   + 256 * 128;
    unsigned short* Wh2c   = Wz2c   + 256 * 128;
    unsigned short* Wp3W3c = Wh2c   + 256 * 128;        // 128*128 combined
    unsigned short* Wr3c   = Wp3W3c + 128 * 128;        // 128*64
    unsigned short* Wz3c   = Wr3c   + 128 * 64;
    unsigned short* Wh3c   = Wz3c   + 128 * 64;
    int* ioff = (int*)(((size_t)(Wh3c + 128 * 64) + 15) & ~(size_t)15);
    int* cnt  = ioff + (Nn + 1);
    int* cur  = cnt + Nn;
    int* csr  = cur + Nn;

    dim3 blk(256);

    // ---------- all 15 weight conversions in ONE launch ----------
    {
        WPack p;
        const float* Ws[15]     = {W_tr, W1, Wr1, Wz1, Wh1,
                                   Wp2, W2, Wr2, Wz2, Wh2,
                                   Wp3, W3, Wr3, Wz3, Wh3};
        unsigned short* Wcs[15] = {Wtrc, W1c, Wr1c, Wz1c, Wh1c,
                                   Wp2W2c, Wp2W2c, Wr2c, Wz2c, Wh2c,
                                   Wp3W3c, Wp3W3c, Wr3c, Wz3c, Wh3c};
        int Ks[15]   = {128, 256, 512, 512, 512, 256, 256, 256, 256, 256, 128, 128, 128, 128, 128};
        int MoSs[15] = {256, 256, 256, 256, 256, 128, 128, 128, 128, 128, 64, 64, 64, 64, 64};
        int MoDs[15] = {256, 256, 256, 256, 256, 256, 256, 128, 128, 128, 128, 128, 64, 64, 64};
        int offs[15] = {0, 0, 0, 0, 0, 0, 128, 0, 0, 0, 0, 64, 0, 0, 0};
        for (int i = 0; i < 15; ++i) {
            p.W[i] = Ws[i]; p.Wc[i] = Wcs[i]; p.K[i] = Ks[i];
            p.MoS[i] = MoSs[i]; p.MoD[i] = MoDs[i]; p.off[i] = offs[i];
        }
        convW_all<<<dim3((512 * 256 + 255) / 256, 15), blk, 0, stream>>>(p);
    }

    // ---------- CSR build ----------
    hipMemsetAsync(cnt, 0, (size_t)Nn * 4, stream);
    hipMemsetAsync(cur, 0, (size_t)Nn * 4, stream);
    count_k<<<(E + 255) / 256, blk, 0, stream>>>(dstp, E, cnt);
    scan_k<<<1, 1024, 0, stream>>>(cnt, Nn, ioff);
    scatter_k<<<(E + 255) / 256, blk, 0, stream>>>(srcp, dstp, E, ioff, cur, csr);

    // ---------- stage 0: X0b = bf16(x @ W_tr + b_tr) ----------
    unsigned short* xb = Gb;   // Gb free until gather1
    conv_k<<<(int)(((long)Nn * 128 / 4 + 255) / 256), blk, 0, stream>>>(x, xb, (long)Nn * 128);
    gemm_t<128,0><<<gblocks(Nn, 256, 128), blk, 0, stream>>>(
        xb, 128, nullptr, 0, Wtrc, b_tr, nullptr, X0b, nullptr,
        nullptr, nullptr, nullptr, nullptr, Nn, 256);

    // ================= layer 1 (D=256, H=8, C=32) =================
    gemm_t<128,0><<<gblocks(Nn, 256, 128), blk, 0, stream>>>(
        X0b, 256, nullptr, 0, W1c, nullptr, nullptr, XPb, nullptr,
        nullptr, nullptr, nullptr, nullptr, Nn, 256);
    alpha_b<<<(Nn * 8 + 255) / 256, blk, 0, stream>>>(XPb, as1, ad1, AS, AD, Nn, 8, 32);
    launch_gather(ioff, csr, XPb, AS, AD, b1, Gb, Nn, 8, 32, 1, stream);
    gemm_rz<0><<<gblocks(Nn, 256, 64), blk, 0, stream>>>(
        Gb, 256, X0b, 256, Wr1c, Wz1c, br1, bz1, X0b, nullptr, RHb, Zb, nullptr, Nn, 256);
    gemm_t<128,3><<<gblocks(Nn, 256, 128), blk, 0, stream>>>(
        Gb, 256, RHb, 256, Wh1c, bh1, nullptr, XPb, nullptr,
        X0b, Zb, nullptr, nullptr, Nn, 256);
    // XPb holds x1 (bf16)

    // ================= layer 2 (D=128, H=4, C=32) =================
    gemm_t<128,4><<<gblocks(Nn, 256, 128), blk, 0, stream>>>(
        XPb, 256, nullptr, 0, Wp2W2c, bp2, nullptr, HINb, X0b,
        nullptr, nullptr, nullptr, nullptr, Nn, 256);
    alpha_b<<<(Nn * 4 + 255) / 256, blk, 0, stream>>>(X0b, as2, ad2, AS, AD, Nn, 4, 32);
    launch_gather(ioff, csr, X0b, AS, AD, b2, Gb, Nn, 4, 32, 1, stream);
    gemm_rz<0><<<gblocks(Nn, 128, 64), blk, 0, stream>>>(
        Gb, 128, HINb, 128, Wr2c, Wz2c, br2, bz2, HINb, nullptr, RHb, Zb, nullptr, Nn, 128);
    gemm_t<128,3><<<gblocks(Nn, 128, 128), blk, 0, stream>>>(
        Gb, 128, RHb, 128, Wh2c, bh2, nullptr, X0b, nullptr,
        HINb, Zb, nullptr, nullptr, Nn, 128);
    // X0b holds x2 (bf16)

    // ================= layer 3 (D=64, H=1, C=64, fp32 state) =================
    unsigned short* H3b  = HINb;                 // [N,64]
    unsigned short* XP3b = HINb + (size_t)Nn * 64;
    gemm_t<128,4><<<gblocks(Nn, 128, 128), blk, 0, stream>>>(
        X0b, 128, nullptr, 0, Wp3W3c, bp3, H3f, H3b, XP3b,
        nullptr, nullptr, nullptr, nullptr, Nn, 128);
    alpha_b<<<(Nn + 255) / 256, blk, 0, stream>>>(XP3b, as3, ad3, AS, AD, Nn, 1, 64);
    launch_gather(ioff, csr, XP3b, AS, AD, b3, Gb, Nn, 1, 64, 0, stream);
    gemm_rz<1><<<gblocks(Nn, 64, 64), blk, 0, stream>>>(
        Gb, 64, H3b, 64, Wr3c, Wz3c, br3, bz3, nullptr, H3f, RHb, nullptr, Z3f, Nn, 64);
    gemm_t<64,5><<<gblocks(Nn, 64, 64), blk, 0, stream>>>(
        Gb, 64, RHb, 64, Wh3c, bh3, (float*)d_out, nullptr, nullptr,
        nullptr, nullptr, H3f, Z3f, Nn, 64);
}

// Round 12
// 663.475 us; speedup vs baseline: 1.1100x; 1.1100x over previous
//
#include <hip/hip_runtime.h>

#define NEG_SLOPE 0.2f

typedef __attribute__((ext_vector_type(8))) short short8;
typedef __attribute__((ext_vector_type(8))) unsigned short ushort8;
typedef __attribute__((ext_vector_type(4))) float f32x4;

__device__ __forceinline__ unsigned short f2bf(float f) {
    unsigned int u = __float_as_uint(f);
    u += 0x7fff + ((u >> 16) & 1);     // round-to-nearest-even
    return (unsigned short)(u >> 16);
}
__device__ __forceinline__ float bf2f(unsigned short s) {
    return __uint_as_float(((unsigned int)s) << 16);
}

// async global->LDS, 16B per lane; lds base must be wave-uniform
__device__ __forceinline__ void gll16(const void* g, void* l) {
    __builtin_amdgcn_global_load_lds(
        (const __attribute__((address_space(1))) void*)g,
        (__attribute__((address_space(3))) void*)l, 16, 0, 0);
}

// ---------------- converters ----------------
__global__ void conv_k(const float* __restrict__ in, unsigned short* __restrict__ out, long n)
{
    long i = ((long)blockIdx.x * blockDim.x + threadIdx.x) * 4;
    if (i >= n) return;
    float4 f = *(const float4*)&in[i];
    ushort4 o; o.x = f2bf(f.x); o.y = f2bf(f.y); o.z = f2bf(f.z); o.w = f2bf(f.w);
    *(ushort4*)&out[i] = o;
}

// all 15 weights in one launch; supports column-offset packing into wider dst:
// Wc[((k>>3)*MoD + off + m)*8 + (k&7)] = bf16(W[k*MoS + m])
struct WPack {
    const float* W[15];
    unsigned short* Wc[15];
    int K[15];
    int MoS[15];
    int MoD[15];
    int off[15];
};
__global__ void convW_all(WPack p)
{
    int wi = blockIdx.y;
    int i = blockIdx.x * blockDim.x + threadIdx.x;
    int K = p.K[wi], MoS = p.MoS[wi];
    if (i >= K * MoS) return;
    int k = i / MoS, m = i % MoS;
    p.Wc[wi][((long)(k >> 3) * p.MoD[wi] + p.off[wi] + m) * 8 + (k & 7)] = f2bf(p.W[wi][i]);
}

// XCD-grouping remap (bijective with pad): consecutive work items share an XCD L2.
__device__ __forceinline__ int xcd_work(int TOT) {
    int L = blockIdx.x;
    int per = (TOT + 7) >> 3;
    int wk = (L & 7) * per + (L >> 3);
    return (wk < TOT) ? wk : -1;
}

// ================= bf16 MFMA GEMM: BM=64, BK=64, 4 waves (2x2) =================
// BN=128: wave tile 32x64 (2x4 frags). BN=64: wave tile 32x32 (2x2 frags).
// MODE 0: outF/outB = acc+bias (either may be null)
// MODE 3: o = (1-z)*hin + z*tanh(acc+bias), z/hin bf16; outB   (GRU finish, L1/L2)
// MODE 4: split projection: col<Mo/2 -> outF/outB = acc+bias[col] ([rows,Mo/2])
//         col>=Mo/2 -> outB2 = bf16(acc)                         ([rows,Mo/2])
// MODE 5: o = (1-Zf)*HinF + Zf*tanh(acc+bias); outF fp32        (GRU finish, L3)
template<int BN, int MODE>
__global__ __launch_bounds__(256) void gemm_t(
    const unsigned short* __restrict__ U, int K1,
    const unsigned short* __restrict__ V, int K2,
    const unsigned short* __restrict__ Wc, const float* __restrict__ bias,
    float* __restrict__ outF, unsigned short* __restrict__ outB,
    unsigned short* __restrict__ outB2,
    const unsigned short* __restrict__ HinB, const unsigned short* __restrict__ Zb,
    const float* __restrict__ HinF, const float* __restrict__ Zf,
    int rows, int Mo)
{
    constexpr int NIF = BN / 32;       // frags per wave in N (WC=2)
    __shared__ __align__(16) unsigned short As[8][64][8];    // 8KB
    __shared__ __align__(16) unsigned short Bs[8][BN][8];    // 16KB / 8KB
    const int CB = Mo / BN;
    const int RB = (rows + 63) >> 6;
    int wk = xcd_work(CB * RB);
    if (wk < 0) return;
    const int col0 = (wk % CB) * BN;
    const int row0 = (wk / CB) * 64;
    const int K = K1 + K2;
    const int tid = threadIdx.x;
    const int l = tid & 63, w = tid >> 6;
    const int lm = l & 15, lg = l >> 4;
    const int wrow = (w >> 1) * 32;
    const int wcol = (w & 1) * (BN / 2);
    f32x4 acc[2][NIF] = {};

    for (int k0 = 0; k0 < K; k0 += 64) {
#pragma unroll
        for (int i = 0; i < 2; ++i) {
            int c = i * 256 + tid;
            int m = c & 63, g = c >> 6;           // g wave-uniform
            int row = row0 + m; if (row >= rows) row = rows - 1;
            int k = k0 + g * 8;
            const unsigned short* sp = (k < K1) ? U + (long)row * K1 + k
                                                : V + (long)row * K2 + (k - K1);
            gll16(sp, &As[0][0][0] + ((i * 256 + w * 64) << 3));
        }
#pragma unroll
        for (int j = 0; j < NIF; ++j) {
            int c = j * 256 + tid;
            int n = c & (BN - 1), g = c / BN;     // g wave-uniform
            gll16(Wc + ((long)((k0 >> 3) + g) * Mo + (col0 + n)) * 8,
                  &Bs[0][0][0] + ((j * 256 + w * 64) << 3));
        }
        __syncthreads();
#pragma unroll
        for (int kk = 0; kk < 2; ++kk) {
            short8 a[2], b[NIF];
#pragma unroll
            for (int mi = 0; mi < 2; ++mi)
                a[mi] = *(const short8*)&As[kk * 4 + lg][wrow + mi * 16 + lm][0];
#pragma unroll
            for (int ni = 0; ni < NIF; ++ni)
                b[ni] = *(const short8*)&Bs[kk * 4 + lg][wcol + ni * 16 + lm][0];
#pragma unroll
            for (int mi = 0; mi < 2; ++mi)
#pragma unroll
                for (int ni = 0; ni < NIF; ++ni)
                    acc[mi][ni] = __builtin_amdgcn_mfma_f32_16x16x32_bf16(a[mi], b[ni], acc[mi][ni], 0, 0, 0);
        }
        __syncthreads();
    }

    const int halfMo = Mo >> 1;
#pragma unroll
    for (int mi = 0; mi < 2; ++mi) {
        int rbase = row0 + wrow + mi * 16 + lg * 4;
#pragma unroll
        for (int r = 0; r < 4; ++r) {
            int row = rbase + r;
            if (row >= rows) continue;
#pragma unroll
            for (int ni = 0; ni < NIF; ++ni) {
                int col = col0 + wcol + ni * 16 + lm;
                float v = acc[mi][ni][r];
                if (MODE == 0) {
                    v += (bias ? bias[col] : 0.f);
                    long idx = (long)row * Mo + col;
                    if (outF) outF[idx] = v;
                    if (outB) outB[idx] = f2bf(v);
                } else if (MODE == 3) {
                    v += bias[col];
                    long idx = (long)row * Mo + col;
                    float z = bf2f(Zb[idx]);
                    float o = (1.f - z) * bf2f(HinB[idx]) + z * tanhf(v);
                    outB[idx] = f2bf(o);
                } else if (MODE == 5) {
                    v += bias[col];
                    long idx = (long)row * Mo + col;
                    float z = Zf[idx];
                    float o = (1.f - z) * HinF[idx] + z * tanhf(v);
                    outF[idx] = o;
                } else {  // MODE 4
                    if (col < halfMo) {
                        v += bias[col];
                        long idx = (long)row * halfMo + col;
                        if (outF) outF[idx] = v;
                        outB[idx] = f2bf(v);
                    } else {
                        outB2[(long)row * halfMo + (col - halfMo)] = f2bf(v);
                    }
                }
            }
        }
    }
}

// ================= fused r+z dual-B GEMM: BM=64, BN=64, shared A =================
// FP=0: hin/z in bf16 (L1/L2);  FP=1: hin/z in fp32 (L3)
//   RHb = bf16( sigmoid(acc_r + br) * hin ),  Zout = sigmoid(acc_z + bz)
template<int FP>
__global__ __launch_bounds__(256) void gemm_rz(
    const unsigned short* __restrict__ U, int K1,
    const unsigned short* __restrict__ V, int K2,
    const unsigned short* __restrict__ Wrc, const unsigned short* __restrict__ Wzc,
    const float* __restrict__ br, const float* __restrict__ bz,
    const unsigned short* __restrict__ HinB, const float* __restrict__ HinF,
    unsigned short* __restrict__ RHb,
    unsigned short* __restrict__ ZoutB, float* __restrict__ ZoutF,
    int rows, int Mo)
{
    __shared__ __align__(16) unsigned short As[8][64][8];   // 8KB
    __shared__ __align__(16) unsigned short Br[8][64][8];   // 8KB
    __shared__ __align__(16) unsigned short Bz[8][64][8];   // 8KB
    const int CB = Mo >> 6;
    const int RB = (rows + 63) >> 6;
    int wk = xcd_work(CB * RB);
    if (wk < 0) return;
    const int col0 = (wk % CB) * 64;
    const int row0 = (wk / CB) * 64;
    const int K = K1 + K2;
    const int tid = threadIdx.x;
    const int l = tid & 63, w = tid >> 6;
    const int lm = l & 15, lg = l >> 4;
    const int wrow = (w >> 1) * 32;
    const int wcol = (w & 1) * 32;
    f32x4 accr[2][2] = {}, accz[2][2] = {};

    for (int k0 = 0; k0 < K; k0 += 64) {
#pragma unroll
        for (int i = 0; i < 2; ++i) {
            int c = i * 256 + tid;
            int m = c & 63, g = c >> 6;
            int row = row0 + m; if (row >= rows) row = rows - 1;
            int k = k0 + g * 8;
            const unsigned short* sp = (k < K1) ? U + (long)row * K1 + k
                                                : V + (long)row * K2 + (k - K1);
            gll16(sp, &As[0][0][0] + ((i * 256 + w * 64) << 3));
        }
#pragma unroll
        for (int j = 0; j < 2; ++j) {
            int c = j * 256 + tid;
            int n = c & 63, g = c >> 6;
            long base = ((long)((k0 >> 3) + g) * Mo + (col0 + n)) * 8;
            gll16(Wrc + base, &Br[0][0][0] + ((j * 256 + w * 64) << 3));
            gll16(Wzc + base, &Bz[0][0][0] + ((j * 256 + w * 64) << 3));
        }
        __syncthreads();
#pragma unroll
        for (int kk = 0; kk < 2; ++kk) {
            short8 a[2], brv[2], bzv[2];
#pragma unroll
            for (int mi = 0; mi < 2; ++mi)
                a[mi] = *(const short8*)&As[kk * 4 + lg][wrow + mi * 16 + lm][0];
#pragma unroll
            for (int ni = 0; ni < 2; ++ni) {
                brv[ni] = *(const short8*)&Br[kk * 4 + lg][wcol + ni * 16 + lm][0];
                bzv[ni] = *(const short8*)&Bz[kk * 4 + lg][wcol + ni * 16 + lm][0];
            }
#pragma unroll
            for (int mi = 0; mi < 2; ++mi)
#pragma unroll
                for (int ni = 0; ni < 2; ++ni) {
                    accr[mi][ni] = __builtin_amdgcn_mfma_f32_16x16x32_bf16(a[mi], brv[ni], accr[mi][ni], 0, 0, 0);
                    accz[mi][ni] = __builtin_amdgcn_mfma_f32_16x16x32_bf16(a[mi], bzv[ni], accz[mi][ni], 0, 0, 0);
                }
        }
        __syncthreads();
    }

#pragma unroll
    for (int mi = 0; mi < 2; ++mi) {
        int rbase = row0 + wrow + mi * 16 + lg * 4;
#pragma unroll
        for (int r = 0; r < 4; ++r) {
            int row = rbase + r;
            if (row >= rows) continue;
#pragma unroll
            for (int ni = 0; ni < 2; ++ni) {
                int col = col0 + wcol + ni * 16 + lm;
                long idx = (long)row * Mo + col;
                float rv = 1.f / (1.f + __expf(-(accr[mi][ni][r] + br[col])));
                float zv = 1.f / (1.f + __expf(-(accz[mi][ni][r] + bz[col])));
                float hin = FP ? HinF[idx] : bf2f(HinB[idx]);
                RHb[idx] = f2bf(rv * hin);
                if (FP) ZoutF[idx] = zv;
                else    ZoutB[idx] = f2bf(zv);
            }
        }
    }
}

// ---------------- alpha (bf16 input, vectorized) ----------------
__global__ void alpha_b(const unsigned short* __restrict__ XPb,
                        const float* __restrict__ a_s, const float* __restrict__ a_d,
                        float* __restrict__ AS, float* __restrict__ AD,
                        int Nn, int H, int C)
{
    int i = blockIdx.x * blockDim.x + threadIdx.x;
    if (i >= Nn * H) return;
    int n = i / H, h = i % H;
    const unsigned short* xp = &XPb[(long)n * H * C + (long)h * C];
    const float* asv = &a_s[h * C];
    const float* adv = &a_d[h * C];
    float ss = 0.f, sd = 0.f;
    for (int c = 0; c < C; c += 8) {
        ushort8 xv = *(const ushort8*)&xp[c];
#pragma unroll
        for (int q = 0; q < 8; ++q) {
            float v = bf2f(xv[q]);
            ss += v * asv[c + q];
            sd += v * adv[c + q];
        }
    }
    AS[i] = ss; AD[i] = sd;
}

// ---------------- CSR build ----------------
__global__ void count_k(const int* __restrict__ dst, int E, int* __restrict__ cnt)
{
    int e = blockIdx.x * blockDim.x + threadIdx.x;
    if (e < E) atomicAdd(&cnt[dst[e]], 1);
}

// exclusive scan; also initializes cur = off so scatter can use atomic result directly
__global__ __launch_bounds__(1024) void scan_k(const int* __restrict__ cnt, int Nn,
                                               int* __restrict__ off, int* __restrict__ cur)
{
    __shared__ int part[1024];
    int tid = threadIdx.x;
    int chunk = (Nn + 1023) / 1024;
    int b = tid * chunk;
    int e = b + chunk; if (e > Nn) e = Nn; if (b > Nn) b = Nn;
    int s = 0;
    for (int i = b; i < e; ++i) s += cnt[i];
    part[tid] = s;
    __syncthreads();
    for (int d = 1; d < 1024; d <<= 1) {
        int v = (tid >= d) ? part[tid - d] : 0;
        __syncthreads();
        part[tid] += v;
        __syncthreads();
    }
    int run = tid ? part[tid - 1] : 0;
    for (int i = b; i < e; ++i) { off[i] = run; cur[i] = run; run += cnt[i]; }
    if (tid == 1023) off[Nn] = part[1023];
}

__global__ void scatter_k(const int* __restrict__ src, const int* __restrict__ dst, int E,
                          int* __restrict__ cur, int* __restrict__ csr_src)
{
    int e = blockIdx.x * blockDim.x + threadIdx.x;
    if (e < E) {
        int p = atomicAdd(&cur[dst[e]], 1);
        csr_src[p] = src[e];
    }
}

// ---------------- bf16 GAT gather (8 feats/lane, 8x-unrolled edge loop) ----------------
__global__ void gat_gather_b(const int* __restrict__ off, const int* __restrict__ csr_src,
                             const unsigned short* __restrict__ XPb,
                             const float* __restrict__ AS, const float* __restrict__ AD,
                             const float* __restrict__ bias,
                             unsigned short* __restrict__ Gout,
                             int Nn, int H, int C, int do_elu)
{
    const int D = H * C;
    const int lpn = D >> 3;
    const int npw = 64 / lpn;
    int lane = threadIdx.x & 63;
    long wave = ((long)blockIdx.x * blockDim.x + threadIdx.x) >> 6;
    int sub = lane / lpn;
    int cl = lane % lpn;
    long n = wave * npw + sub;
    if (n >= Nn) return;
    int j = cl * 8;
    int h = j / C;
    float ad = AD[n * H + h];
    float v = AS[n * H + h] + ad;
    v = v > 0.f ? v : NEG_SLOPE * v;
    float w = __expf(v);
    float den = w;
    float acc[8];
    {
        ushort8 xv = *(const ushort8*)&XPb[(long)n * D + j];
#pragma unroll
        for (int q = 0; q < 8; ++q) acc[q] = w * bf2f(xv[q]);
    }
    int b0 = off[n], b1 = off[n + 1];
    int i = b0;
    for (; i + 8 <= b1; i += 8) {
        int s[8];
#pragma unroll
        for (int u = 0; u < 8; ++u) s[u] = csr_src[i + u];
        float wv[8];
#pragma unroll
        for (int u = 0; u < 8; ++u) {
            float vv = AS[s[u] * H + h] + ad;
            vv = vv > 0.f ? vv : NEG_SLOPE * vv;
            wv[u] = __expf(vv);
        }
#pragma unroll
        for (int u = 0; u < 8; ++u) den += wv[u];
        ushort8 xv[8];
#pragma unroll
        for (int u = 0; u < 8; ++u) xv[u] = *(const ushort8*)&XPb[(long)s[u] * D + j];
#pragma unroll
        for (int q = 0; q < 8; ++q) {
            float a0 = wv[0] * bf2f(xv[0][q]) + wv[1] * bf2f(xv[1][q]);
            float a1 = wv[2] * bf2f(xv[2][q]) + wv[3] * bf2f(xv[3][q]);
            float a2 = wv[4] * bf2f(xv[4][q]) + wv[5] * bf2f(xv[5][q]);
            float a3 = wv[6] * bf2f(xv[6][q]) + wv[7] * bf2f(xv[7][q]);
            acc[q] += (a0 + a1) + (a2 + a3);
        }
    }
    for (; i < b1; ++i) {
        int s = csr_src[i];
        v = AS[s * H + h] + ad;
        v = v > 0.f ? v : NEG_SLOPE * v;
        w = __expf(v);
        den += w;
        ushort8 xv = *(const ushort8*)&XPb[(long)s * D + j];
#pragma unroll
        for (int q = 0; q < 8; ++q) acc[q] += w * bf2f(xv[q]);
    }
    float inv = 1.f / (den + 1e-16f);
    ushort8 ov;
#pragma unroll
    for (int q = 0; q < 8; ++q) {
        float o = acc[q] * inv + bias[j + q];
        if (do_elu) o = o > 0.f ? o : expm1f(o);
        ov[q] = f2bf(o);
    }
    *(ushort8*)&Gout[(long)n * D + j] = ov;
}

static inline int pad8(int t) { return ((t + 7) / 8) * 8; }
static inline int gblocks(int rows, int Mo, int BN) {
    return pad8((Mo / BN) * ((rows + 63) >> 6));
}

static inline void launch_gather(const int* ioff, const int* csr,
                                 const unsigned short* xp, const float* AS, const float* AD,
                                 const float* bias, unsigned short* gout,
                                 int Nn, int H, int C, int elu, hipStream_t stream)
{
    int D = H * C;
    int lpn = D >> 3;
    int npw = 64 / lpn;
    long waves = (Nn + npw - 1) / npw;
    int blocks = (int)((waves * 64 + 255) / 256);
    gat_gather_b<<<blocks, 256, 0, stream>>>(ioff, csr, xp, AS, AD, bias, gout, Nn, H, C, elu);
}

extern "C" void kernel_launch(void* const* d_in, const int* in_sizes, int n_in,
                              void* d_out, int out_size, void* d_ws, size_t ws_size,
                              hipStream_t stream)
{
    const float* x    = (const float*)d_in[0];
    const int*   ei   = (const int*)  d_in[1];
    const float* W_tr = (const float*)d_in[2];
    const float* b_tr = (const float*)d_in[3];
    const float* W1   = (const float*)d_in[4];
    const float* as1  = (const float*)d_in[5];
    const float* ad1  = (const float*)d_in[6];
    const float* b1   = (const float*)d_in[7];
    const float* Wr1  = (const float*)d_in[8];
    const float* br1  = (const float*)d_in[9];
    const float* Wz1  = (const float*)d_in[10];
    const float* bz1  = (const float*)d_in[11];
    const float* Wh1  = (const float*)d_in[12];
    const float* bh1  = (const float*)d_in[13];
    const float* Wp2  = (const float*)d_in[14];
    const float* bp2  = (const float*)d_in[15];
    const float* W2   = (const float*)d_in[16];
    const float* as2  = (const float*)d_in[17];
    const float* ad2  = (const float*)d_in[18];
    const float* b2   = (const float*)d_in[19];
    const float* Wr2  = (const float*)d_in[20];
    const float* br2  = (const float*)d_in[21];
    const float* Wz2  = (const float*)d_in[22];
    const float* bz2  = (const float*)d_in[23];
    const float* Wh2  = (const float*)d_in[24];
    const float* bh2  = (const float*)d_in[25];
    const float* Wp3  = (const float*)d_in[26];
    const float* bp3  = (const float*)d_in[27];
    const float* W3   = (const float*)d_in[28];
    const float* as3  = (const float*)d_in[29];
    const float* ad3  = (const float*)d_in[30];
    const float* b3   = (const float*)d_in[31];
    const float* Wr3  = (const float*)d_in[32];
    const float* br3  = (const float*)d_in[33];
    const float* Wz3  = (const float*)d_in[34];
    const float* bz3  = (const float*)d_in[35];
    const float* Wh3  = (const float*)d_in[36];
    const float* bh3  = (const float*)d_in[37];

    const int Nn = in_sizes[0] / 128;   // 50000
    const int E  = in_sizes[1] / 2;     // 800000
    const int* srcp = ei;
    const int* dstp = ei + E;

    // ---------------- workspace layout (bf16-state) ----------------
    float* AS  = (float*)d_ws;                          // [N,8]
    float* AD  = AS + (size_t)Nn * 8;                   // [N,8]
    float* H3f = AD + (size_t)Nn * 8;                   // [N,64] fp32 (L3 h_in)
    float* Z3f = H3f + (size_t)Nn * 64;                 // [N,64] fp32 (L3 z)
    unsigned short* X0b  = (unsigned short*)(Z3f + (size_t)Nn * 64); // [N,256]
    unsigned short* XPb  = X0b + (size_t)Nn * 256;      // [N,256]
    unsigned short* Gb   = XPb + (size_t)Nn * 256;      // [N,256]
    unsigned short* RHb  = Gb  + (size_t)Nn * 256;      // [N,256]
    unsigned short* HINb = RHb + (size_t)Nn * 256;      // [N,128]
    unsigned short* Zb   = HINb + (size_t)Nn * 128;     // [N,256]
    unsigned short* wpool = Zb + (size_t)Nn * 256;
    unsigned short* Wtrc   = wpool;                     // 128*256
    unsigned short* W1c    = Wtrc   + 128 * 256;        // 256*256
    unsigned short* Wr1c   = W1c    + 256 * 256;        // 512*256
    unsigned short* Wz1c   = Wr1c   + 512 * 256;
    unsigned short* Wh1c   = Wz1c   + 512 * 256;
    unsigned short* Wp2W2c = Wh1c   + 512 * 256;        // 256*256 combined
    unsigned short* Wr2c   = Wp2W2c + 256 * 256;        // 256*128
    unsigned short* Wz2c   = Wr2c   + 256 * 128;
    unsigned short* Wh2c   = Wz2c   + 256 * 128;
    unsigned short* Wp3W3c = Wh2c   + 256 * 128;        // 128*128 combined
    unsigned short* Wr3c   = Wp3W3c + 128 * 128;        // 128*64
    unsigned short* Wz3c   = Wr3c   + 128 * 64;
    unsigned short* Wh3c   = Wz3c   + 128 * 64;
    int* ioff = (int*)(((size_t)(Wh3c + 128 * 64) + 15) & ~(size_t)15);
    int* cnt  = ioff + (Nn + 1);
    int* cur  = cnt + Nn;
    int* csr  = cur + Nn;

    dim3 blk(256);

    // ---------- all 15 weight conversions in ONE launch ----------
    {
        WPack p;
        const float* Ws[15]     = {W_tr, W1, Wr1, Wz1, Wh1,
                                   Wp2, W2, Wr2, Wz2, Wh2,
                                   Wp3, W3, Wr3, Wz3, Wh3};
        unsigned short* Wcs[15] = {Wtrc, W1c, Wr1c, Wz1c, Wh1c,
                                   Wp2W2c, Wp2W2c, Wr2c, Wz2c, Wh2c,
                                   Wp3W3c, Wp3W3c, Wr3c, Wz3c, Wh3c};
        int Ks[15]   = {128, 256, 512, 512, 512, 256, 256, 256, 256, 256, 128, 128, 128, 128, 128};
        int MoSs[15] = {256, 256, 256, 256, 256, 128, 128, 128, 128, 128, 64, 64, 64, 64, 64};
        int MoDs[15] = {256, 256, 256, 256, 256, 256, 256, 128, 128, 128, 128, 128, 64, 64, 64};
        int offs[15] = {0, 0, 0, 0, 0, 0, 128, 0, 0, 0, 0, 64, 0, 0, 0};
        for (int i = 0; i < 15; ++i) {
            p.W[i] = Ws[i]; p.Wc[i] = Wcs[i]; p.K[i] = Ks[i];
            p.MoS[i] = MoSs[i]; p.MoD[i] = MoDs[i]; p.off[i] = offs[i];
        }
        convW_all<<<dim3((512 * 256 + 255) / 256, 15), blk, 0, stream>>>(p);
    }

    // ---------- CSR build ----------
    hipMemsetAsync(cnt, 0, (size_t)Nn * 4, stream);
    count_k<<<(E + 255) / 256, blk, 0, stream>>>(dstp, E, cnt);
    scan_k<<<1, 1024, 0, stream>>>(cnt, Nn, ioff, cur);
    scatter_k<<<(E + 255) / 256, blk, 0, stream>>>(srcp, dstp, E, cur, csr);

    // ---------- stage 0: X0b = bf16(x @ W_tr + b_tr) ----------
    unsigned short* xb = Gb;   // Gb free until gather1
    conv_k<<<(int)(((long)Nn * 128 / 4 + 255) / 256), blk, 0, stream>>>(x, xb, (long)Nn * 128);
    gemm_t<128,0><<<gblocks(Nn, 256, 128), blk, 0, stream>>>(
        xb, 128, nullptr, 0, Wtrc, b_tr, nullptr, X0b, nullptr,
        nullptr, nullptr, nullptr, nullptr, Nn, 256);

    // ================= layer 1 (D=256, H=8, C=32) =================
    gemm_t<128,0><<<gblocks(Nn, 256, 128), blk, 0, stream>>>(
        X0b, 256, nullptr, 0, W1c, nullptr, nullptr, XPb, nullptr,
        nullptr, nullptr, nullptr, nullptr, Nn, 256);
    alpha_b<<<(Nn * 8 + 255) / 256, blk, 0, stream>>>(XPb, as1, ad1, AS, AD, Nn, 8, 32);
    launch_gather(ioff, csr, XPb, AS, AD, b1, Gb, Nn, 8, 32, 1, stream);
    gemm_rz<0><<<gblocks(Nn, 256, 64), blk, 0, stream>>>(
        Gb, 256, X0b, 256, Wr1c, Wz1c, br1, bz1, X0b, nullptr, RHb, Zb, nullptr, Nn, 256);
    gemm_t<128,3><<<gblocks(Nn, 256, 128), blk, 0, stream>>>(
        Gb, 256, RHb, 256, Wh1c, bh1, nullptr, XPb, nullptr,
        X0b, Zb, nullptr, nullptr, Nn, 256);
    // XPb holds x1 (bf16)

    // ================= layer 2 (D=128, H=4, C=32) =================
    gemm_t<128,4><<<gblocks(Nn, 256, 128), blk, 0, stream>>>(
        XPb, 256, nullptr, 0, Wp2W2c, bp2, nullptr, HINb, X0b,
        nullptr, nullptr, nullptr, nullptr, Nn, 256);
    alpha_b<<<(Nn * 4 + 255) / 256, blk, 0, stream>>>(X0b, as2, ad2, AS, AD, Nn, 4, 32);
    launch_gather(ioff, csr, X0b, AS, AD, b2, Gb, Nn, 4, 32, 1, stream);
    gemm_rz<0><<<gblocks(Nn, 128, 64), blk, 0, stream>>>(
        Gb, 128, HINb, 128, Wr2c, Wz2c, br2, bz2, HINb, nullptr, RHb, Zb, nullptr, Nn, 128);
    gemm_t<128,3><<<gblocks(Nn, 128, 128), blk, 0, stream>>>(
        Gb, 128, RHb, 128, Wh2c, bh2, nullptr, X0b, nullptr,
        HINb, Zb, nullptr, nullptr, Nn, 128);
    // X0b holds x2 (bf16)

    // ================= layer 3 (D=64, H=1, C=64, fp32 state) =================
    unsigned short* H3b  = HINb;                 // [N,64]
    unsigned short* XP3b = HINb + (size_t)Nn * 64;
    gemm_t<128,4><<<gblocks(Nn, 128, 128), blk, 0, stream>>>(
        X0b, 128, nullptr, 0, Wp3W3c, bp3, H3f, H3b, XP3b,
        nullptr, nullptr, nullptr, nullptr, Nn, 128);
    alpha_b<<<(Nn + 255) / 256, blk, 0, stream>>>(XP3b, as3, ad3, AS, AD, Nn, 1, 64);
    launch_gather(ioff, csr, XP3b, AS, AD, b3, Gb, Nn, 1, 64, 0, stream);
    gemm_rz<1><<<gblocks(Nn, 64, 64), blk, 0, stream>>>(
        Gb, 64, H3b, 64, Wr3c, Wz3c, br3, bz3, nullptr, H3f, RHb, nullptr, Z3f, Nn, 64);
    gemm_t<64,5><<<gblocks(Nn, 64, 64), blk, 0, stream>>>(
        Gb, 64, RHb, 64, Wh3c, bh3, (float*)d_out, nullptr, nullptr,
        nullptr, nullptr, H3f, Z3f, Nn, 64);
}

// Round 13
// 573.951 us; speedup vs baseline: 1.2831x; 1.1560x over previous
//
#include <hip/hip_runtime.h>

#define NEG_SLOPE 0.2f

typedef __attribute__((ext_vector_type(8))) short short8;
typedef __attribute__((ext_vector_type(8))) unsigned short ushort8;
typedef __attribute__((ext_vector_type(4))) float f32x4;

__device__ __forceinline__ unsigned short f2bf(float f) {
    unsigned int u = __float_as_uint(f);
    u += 0x7fff + ((u >> 16) & 1);     // round-to-nearest-even
    return (unsigned short)(u >> 16);
}
__device__ __forceinline__ float bf2f(unsigned short s) {
    return __uint_as_float(((unsigned int)s) << 16);
}

// async global->LDS, 16B per lane; lds base must be wave-uniform
__device__ __forceinline__ void gll16(const void* g, void* l) {
    __builtin_amdgcn_global_load_lds(
        (const __attribute__((address_space(1))) void*)g,
        (__attribute__((address_space(3))) void*)l, 16, 0, 0);
}

// ---------------- converters ----------------
__global__ void conv_k(const float* __restrict__ in, unsigned short* __restrict__ out, long n)
{
    long i = ((long)blockIdx.x * blockDim.x + threadIdx.x) * 4;
    if (i >= n) return;
    float4 f = *(const float4*)&in[i];
    ushort4 o; o.x = f2bf(f.x); o.y = f2bf(f.y); o.z = f2bf(f.z); o.w = f2bf(f.w);
    *(ushort4*)&out[i] = o;
}

// all 15 weights in one launch; supports column-offset packing into wider dst:
// Wc[((k>>3)*MoD + off + m)*8 + (k&7)] = bf16(W[k*MoS + m])
struct WPack {
    const float* W[15];
    unsigned short* Wc[15];
    int K[15];
    int MoS[15];
    int MoD[15];
    int off[15];
};
__global__ void convW_all(WPack p)
{
    int wi = blockIdx.y;
    int i = blockIdx.x * blockDim.x + threadIdx.x;
    int K = p.K[wi], MoS = p.MoS[wi];
    if (i >= K * MoS) return;
    int k = i / MoS, m = i % MoS;
    p.Wc[wi][((long)(k >> 3) * p.MoD[wi] + p.off[wi] + m) * 8 + (k & 7)] = f2bf(p.W[wi][i]);
}

// XCD-grouping remap (bijective with pad): consecutive work items share an XCD L2.
__device__ __forceinline__ int xcd_work(int TOT) {
    int L = blockIdx.x;
    int per = (TOT + 7) >> 3;
    int wk = (L & 7) * per + (L >> 3);
    return (wk < TOT) ? wk : -1;
}

// ================= bf16 MFMA GEMM: BM=64, BK=64, 4 waves (2x2) =================
// MODE 0: outF/outB = acc+bias (either may be null)
// MODE 3: o = (1-z)*hin + z*tanh(acc+bias), z/hin bf16; outB   (GRU finish, L1/L2)
// MODE 4: split projection: col<Mo/2 -> outF/outB = acc+bias[col]; col>=Mo/2 -> outB2
// MODE 5: o = (1-Zf)*HinF + Zf*tanh(acc+bias); outF fp32        (GRU finish, L3)
template<int BN, int MODE>
__global__ __launch_bounds__(256) void gemm_t(
    const unsigned short* __restrict__ U, int K1,
    const unsigned short* __restrict__ V, int K2,
    const unsigned short* __restrict__ Wc, const float* __restrict__ bias,
    float* __restrict__ outF, unsigned short* __restrict__ outB,
    unsigned short* __restrict__ outB2,
    const unsigned short* __restrict__ HinB, const unsigned short* __restrict__ Zb,
    const float* __restrict__ HinF, const float* __restrict__ Zf,
    int rows, int Mo)
{
    constexpr int NIF = BN / 32;       // frags per wave in N (WC=2)
    __shared__ __align__(16) unsigned short As[8][64][8];    // 8KB
    __shared__ __align__(16) unsigned short Bs[8][BN][8];    // 16KB / 8KB
    const int CB = Mo / BN;
    const int RB = (rows + 63) >> 6;
    int wk = xcd_work(CB * RB);
    if (wk < 0) return;
    const int col0 = (wk % CB) * BN;
    const int row0 = (wk / CB) * 64;
    const int K = K1 + K2;
    const int tid = threadIdx.x;
    const int l = tid & 63, w = tid >> 6;
    const int lm = l & 15, lg = l >> 4;
    const int wrow = (w >> 1) * 32;
    const int wcol = (w & 1) * (BN / 2);
    f32x4 acc[2][NIF] = {};

    for (int k0 = 0; k0 < K; k0 += 64) {
#pragma unroll
        for (int i = 0; i < 2; ++i) {
            int c = i * 256 + tid;
            int m = c & 63, g = c >> 6;           // g wave-uniform
            int row = row0 + m; if (row >= rows) row = rows - 1;
            int k = k0 + g * 8;
            const unsigned short* sp = (k < K1) ? U + (long)row * K1 + k
                                                : V + (long)row * K2 + (k - K1);
            gll16(sp, &As[0][0][0] + ((i * 256 + w * 64) << 3));
        }
#pragma unroll
        for (int j = 0; j < NIF; ++j) {
            int c = j * 256 + tid;
            int n = c & (BN - 1), g = c / BN;     // g wave-uniform
            gll16(Wc + ((long)((k0 >> 3) + g) * Mo + (col0 + n)) * 8,
                  &Bs[0][0][0] + ((j * 256 + w * 64) << 3));
        }
        __syncthreads();
#pragma unroll
        for (int kk = 0; kk < 2; ++kk) {
            short8 a[2], b[NIF];
#pragma unroll
            for (int mi = 0; mi < 2; ++mi)
                a[mi] = *(const short8*)&As[kk * 4 + lg][wrow + mi * 16 + lm][0];
#pragma unroll
            for (int ni = 0; ni < NIF; ++ni)
                b[ni] = *(const short8*)&Bs[kk * 4 + lg][wcol + ni * 16 + lm][0];
#pragma unroll
            for (int mi = 0; mi < 2; ++mi)
#pragma unroll
                for (int ni = 0; ni < NIF; ++ni)
                    acc[mi][ni] = __builtin_amdgcn_mfma_f32_16x16x32_bf16(a[mi], b[ni], acc[mi][ni], 0, 0, 0);
        }
        __syncthreads();
    }

    const int halfMo = Mo >> 1;
#pragma unroll
    for (int mi = 0; mi < 2; ++mi) {
        int rbase = row0 + wrow + mi * 16 + lg * 4;
#pragma unroll
        for (int r = 0; r < 4; ++r) {
            int row = rbase + r;
            if (row >= rows) continue;
#pragma unroll
            for (int ni = 0; ni < NIF; ++ni) {
                int col = col0 + wcol + ni * 16 + lm;
                float v = acc[mi][ni][r];
                if (MODE == 0) {
                    v += (bias ? bias[col] : 0.f);
                    long idx = (long)row * Mo + col;
                    if (outF) outF[idx] = v;
                    if (outB) outB[idx] = f2bf(v);
                } else if (MODE == 3) {
                    v += bias[col];
                    long idx = (long)row * Mo + col;
                    float z = bf2f(Zb[idx]);
                    float o = (1.f - z) * bf2f(HinB[idx]) + z * tanhf(v);
                    outB[idx] = f2bf(o);
                } else if (MODE == 5) {
                    v += bias[col];
                    long idx = (long)row * Mo + col;
                    float z = Zf[idx];
                    float o = (1.f - z) * HinF[idx] + z * tanhf(v);
                    outF[idx] = o;
                } else {  // MODE 4
                    if (col < halfMo) {
                        v += bias[col];
                        long idx = (long)row * halfMo + col;
                        if (outF) outF[idx] = v;
                        outB[idx] = f2bf(v);
                    } else {
                        outB2[(long)row * halfMo + (col - halfMo)] = f2bf(v);
                    }
                }
            }
        }
    }
}

// ================= fused r+z dual-B GEMM: BM=64, BN=64, shared A =================
template<int FP>
__global__ __launch_bounds__(256) void gemm_rz(
    const unsigned short* __restrict__ U, int K1,
    const unsigned short* __restrict__ V, int K2,
    const unsigned short* __restrict__ Wrc, const unsigned short* __restrict__ Wzc,
    const float* __restrict__ br, const float* __restrict__ bz,
    const unsigned short* __restrict__ HinB, const float* __restrict__ HinF,
    unsigned short* __restrict__ RHb,
    unsigned short* __restrict__ ZoutB, float* __restrict__ ZoutF,
    int rows, int Mo)
{
    __shared__ __align__(16) unsigned short As[8][64][8];   // 8KB
    __shared__ __align__(16) unsigned short Br[8][64][8];   // 8KB
    __shared__ __align__(16) unsigned short Bz[8][64][8];   // 8KB
    const int CB = Mo >> 6;
    const int RB = (rows + 63) >> 6;
    int wk = xcd_work(CB * RB);
    if (wk < 0) return;
    const int col0 = (wk % CB) * 64;
    const int row0 = (wk / CB) * 64;
    const int K = K1 + K2;
    const int tid = threadIdx.x;
    const int l = tid & 63, w = tid >> 6;
    const int lm = l & 15, lg = l >> 4;
    const int wrow = (w >> 1) * 32;
    const int wcol = (w & 1) * 32;
    f32x4 accr[2][2] = {}, accz[2][2] = {};

    for (int k0 = 0; k0 < K; k0 += 64) {
#pragma unroll
        for (int i = 0; i < 2; ++i) {
            int c = i * 256 + tid;
            int m = c & 63, g = c >> 6;
            int row = row0 + m; if (row >= rows) row = rows - 1;
            int k = k0 + g * 8;
            const unsigned short* sp = (k < K1) ? U + (long)row * K1 + k
                                                : V + (long)row * K2 + (k - K1);
            gll16(sp, &As[0][0][0] + ((i * 256 + w * 64) << 3));
        }
#pragma unroll
        for (int j = 0; j < 2; ++j) {
            int c = j * 256 + tid;
            int n = c & 63, g = c >> 6;
            long base = ((long)((k0 >> 3) + g) * Mo + (col0 + n)) * 8;
            gll16(Wrc + base, &Br[0][0][0] + ((j * 256 + w * 64) << 3));
            gll16(Wzc + base, &Bz[0][0][0] + ((j * 256 + w * 64) << 3));
        }
        __syncthreads();
#pragma unroll
        for (int kk = 0; kk < 2; ++kk) {
            short8 a[2], brv[2], bzv[2];
#pragma unroll
            for (int mi = 0; mi < 2; ++mi)
                a[mi] = *(const short8*)&As[kk * 4 + lg][wrow + mi * 16 + lm][0];
#pragma unroll
            for (int ni = 0; ni < 2; ++ni) {
                brv[ni] = *(const short8*)&Br[kk * 4 + lg][wcol + ni * 16 + lm][0];
                bzv[ni] = *(const short8*)&Bz[kk * 4 + lg][wcol + ni * 16 + lm][0];
            }
#pragma unroll
            for (int mi = 0; mi < 2; ++mi)
#pragma unroll
                for (int ni = 0; ni < 2; ++ni) {
                    accr[mi][ni] = __builtin_amdgcn_mfma_f32_16x16x32_bf16(a[mi], brv[ni], accr[mi][ni], 0, 0, 0);
                    accz[mi][ni] = __builtin_amdgcn_mfma_f32_16x16x32_bf16(a[mi], bzv[ni], accz[mi][ni], 0, 0, 0);
                }
        }
        __syncthreads();
    }

#pragma unroll
    for (int mi = 0; mi < 2; ++mi) {
        int rbase = row0 + wrow + mi * 16 + lg * 4;
#pragma unroll
        for (int r = 0; r < 4; ++r) {
            int row = rbase + r;
            if (row >= rows) continue;
#pragma unroll
            for (int ni = 0; ni < 2; ++ni) {
                int col = col0 + wcol + ni * 16 + lm;
                long idx = (long)row * Mo + col;
                float rv = 1.f / (1.f + __expf(-(accr[mi][ni][r] + br[col])));
                float zv = 1.f / (1.f + __expf(-(accz[mi][ni][r] + bz[col])));
                float hin = FP ? HinF[idx] : bf2f(HinB[idx]);
                RHb[idx] = f2bf(rv * hin);
                if (FP) ZoutF[idx] = zv;
                else    ZoutB[idx] = f2bf(zv);
            }
        }
    }
}

// ---------------- alpha (bf16 input, vectorized) ----------------
__global__ void alpha_b(const unsigned short* __restrict__ XPb,
                        const float* __restrict__ a_s, const float* __restrict__ a_d,
                        float* __restrict__ AS, float* __restrict__ AD,
                        int Nn, int H, int C)
{
    int i = blockIdx.x * blockDim.x + threadIdx.x;
    if (i >= Nn * H) return;
    int n = i / H, h = i % H;
    const unsigned short* xp = &XPb[(long)n * H * C + (long)h * C];
    const float* asv = &a_s[h * C];
    const float* adv = &a_d[h * C];
    float ss = 0.f, sd = 0.f;
    for (int c = 0; c < C; c += 8) {
        ushort8 xv = *(const ushort8*)&xp[c];
#pragma unroll
        for (int q = 0; q < 8; ++q) {
            float v = bf2f(xv[q]);
            ss += v * asv[c + q];
            sd += v * adv[c + q];
        }
    }
    AS[i] = ss; AD[i] = sd;
}

// ---------------- CSR build: parallel 3-phase scan ----------------
__global__ void count_k(const int* __restrict__ dst, int E, int* __restrict__ cnt)
{
    int e = blockIdx.x * blockDim.x + threadIdx.x;
    if (e < E) atomicAdd(&cnt[dst[e]], 1);
}

// phase 1: per-block exclusive scan of 256-element chunks + block sums
__global__ __launch_bounds__(256) void scan1(const int* __restrict__ cnt, int Nn,
                                             int* __restrict__ off, int* __restrict__ bsum)
{
    __shared__ int tmp[256];
    int gid = blockIdx.x * 256 + threadIdx.x;
    int v = (gid < Nn) ? cnt[gid] : 0;
    tmp[threadIdx.x] = v;
    __syncthreads();
    for (int d = 1; d < 256; d <<= 1) {
        int t = (threadIdx.x >= (unsigned)d) ? tmp[threadIdx.x - d] : 0;
        __syncthreads();
        tmp[threadIdx.x] += t;
        __syncthreads();
    }
    if (gid < Nn) off[gid] = tmp[threadIdx.x] - v;   // exclusive within block
    if (threadIdx.x == 255) bsum[blockIdx.x] = tmp[255];
}

// phase 2: single-block exclusive scan of block sums; also writes off[Nn] = E
__global__ __launch_bounds__(256) void scan2(int* __restrict__ bsum, int nb,
                                             int* __restrict__ off, int Nn, int E)
{
    __shared__ int tmp[256];
    int v = (threadIdx.x < (unsigned)nb) ? bsum[threadIdx.x] : 0;
    tmp[threadIdx.x] = v;
    __syncthreads();
    for (int d = 1; d < 256; d <<= 1) {
        int t = (threadIdx.x >= (unsigned)d) ? tmp[threadIdx.x - d] : 0;
        __syncthreads();
        tmp[threadIdx.x] += t;
        __syncthreads();
    }
    if (threadIdx.x < (unsigned)nb) bsum[threadIdx.x] = tmp[threadIdx.x] - v;
    if (threadIdx.x == 0) off[Nn] = E;
}

// phase 3: fold block offsets, init cur
__global__ void scan3(int* __restrict__ off, const int* __restrict__ bsum,
                      int* __restrict__ cur, int Nn)
{
    int gid = blockIdx.x * blockDim.x + threadIdx.x;
    if (gid < Nn) {
        int o = off[gid] + bsum[gid >> 8];
        off[gid] = o;
        cur[gid] = o;
    }
}

__global__ void scatter_k(const int* __restrict__ src, const int* __restrict__ dst, int E,
                          int* __restrict__ cur, int* __restrict__ csr_src)
{
    int e = blockIdx.x * blockDim.x + threadIdx.x;
    if (e < E) {
        int p = atomicAdd(&cur[dst[e]], 1);
        csr_src[p] = src[e];
    }
}

// ---------------- bf16 GAT gather (8 feats/lane, 8x-unrolled edge loop) ----------------
__global__ void gat_gather_b(const int* __restrict__ off, const int* __restrict__ csr_src,
                             const unsigned short* __restrict__ XPb,
                             const float* __restrict__ AS, const float* __restrict__ AD,
                             const float* __restrict__ bias,
                             unsigned short* __restrict__ Gout,
                             int Nn, int H, int C, int do_elu)
{
    const int D = H * C;
    const int lpn = D >> 3;
    const int npw = 64 / lpn;
    int lane = threadIdx.x & 63;
    long wave = ((long)blockIdx.x * blockDim.x + threadIdx.x) >> 6;
    int sub = lane / lpn;
    int cl = lane % lpn;
    long n = wave * npw + sub;
    if (n >= Nn) return;
    int j = cl * 8;
    int h = j / C;
    float ad = AD[n * H + h];
    float v = AS[n * H + h] + ad;
    v = v > 0.f ? v : NEG_SLOPE * v;
    float w = __expf(v);
    float den = w;
    float acc[8];
    {
        ushort8 xv = *(const ushort8*)&XPb[(long)n * D + j];
#pragma unroll
        for (int q = 0; q < 8; ++q) acc[q] = w * bf2f(xv[q]);
    }
    int b0 = off[n], b1 = off[n + 1];
    int i = b0;
    for (; i + 8 <= b1; i += 8) {
        int s[8];
#pragma unroll
        for (int u = 0; u < 8; ++u) s[u] = csr_src[i + u];
        float wv[8];
#pragma unroll
        for (int u = 0; u < 8; ++u) {
            float vv = AS[s[u] * H + h] + ad;
            vv = vv > 0.f ? vv : NEG_SLOPE * vv;
            wv[u] = __expf(vv);
        }
#pragma unroll
        for (int u = 0; u < 8; ++u) den += wv[u];
        ushort8 xv[8];
#pragma unroll
        for (int u = 0; u < 8; ++u) xv[u] = *(const ushort8*)&XPb[(long)s[u] * D + j];
#pragma unroll
        for (int q = 0; q < 8; ++q) {
            float a0 = wv[0] * bf2f(xv[0][q]) + wv[1] * bf2f(xv[1][q]);
            float a1 = wv[2] * bf2f(xv[2][q]) + wv[3] * bf2f(xv[3][q]);
            float a2 = wv[4] * bf2f(xv[4][q]) + wv[5] * bf2f(xv[5][q]);
            float a3 = wv[6] * bf2f(xv[6][q]) + wv[7] * bf2f(xv[7][q]);
            acc[q] += (a0 + a1) + (a2 + a3);
        }
    }
    for (; i < b1; ++i) {
        int s = csr_src[i];
        v = AS[s * H + h] + ad;
        v = v > 0.f ? v : NEG_SLOPE * v;
        w = __expf(v);
        den += w;
        ushort8 xv = *(const ushort8*)&XPb[(long)s * D + j];
#pragma unroll
        for (int q = 0; q < 8; ++q) acc[q] += w * bf2f(xv[q]);
    }
    float inv = 1.f / (den + 1e-16f);
    ushort8 ov;
#pragma unroll
    for (int q = 0; q < 8; ++q) {
        float o = acc[q] * inv + bias[j + q];
        if (do_elu) o = o > 0.f ? o : expm1f(o);
        ov[q] = f2bf(o);
    }
    *(ushort8*)&Gout[(long)n * D + j] = ov;
}

static inline int pad8(int t) { return ((t + 7) / 8) * 8; }
static inline int gblocks(int rows, int Mo, int BN) {
    return pad8((Mo / BN) * ((rows + 63) >> 6));
}

static inline void launch_gather(const int* ioff, const int* csr,
                                 const unsigned short* xp, const float* AS, const float* AD,
                                 const float* bias, unsigned short* gout,
                                 int Nn, int H, int C, int elu, hipStream_t stream)
{
    int D = H * C;
    int lpn = D >> 3;
    int npw = 64 / lpn;
    long waves = (Nn + npw - 1) / npw;
    int blocks = (int)((waves * 64 + 255) / 256);
    gat_gather_b<<<blocks, 256, 0, stream>>>(ioff, csr, xp, AS, AD, bias, gout, Nn, H, C, elu);
}

extern "C" void kernel_launch(void* const* d_in, const int* in_sizes, int n_in,
                              void* d_out, int out_size, void* d_ws, size_t ws_size,
                              hipStream_t stream)
{
    const float* x    = (const float*)d_in[0];
    const int*   ei   = (const int*)  d_in[1];
    const float* W_tr = (const float*)d_in[2];
    const float* b_tr = (const float*)d_in[3];
    const float* W1   = (const float*)d_in[4];
    const float* as1  = (const float*)d_in[5];
    const float* ad1  = (const float*)d_in[6];
    const float* b1   = (const float*)d_in[7];
    const float* Wr1  = (const float*)d_in[8];
    const float* br1  = (const float*)d_in[9];
    const float* Wz1  = (const float*)d_in[10];
    const float* bz1  = (const float*)d_in[11];
    const float* Wh1  = (const float*)d_in[12];
    const float* bh1  = (const float*)d_in[13];
    const float* Wp2  = (const float*)d_in[14];
    const float* bp2  = (const float*)d_in[15];
    const float* W2   = (const float*)d_in[16];
    const float* as2  = (const float*)d_in[17];
    const float* ad2  = (const float*)d_in[18];
    const float* b2   = (const float*)d_in[19];
    const float* Wr2  = (const float*)d_in[20];
    const float* br2  = (const float*)d_in[21];
    const float* Wz2  = (const float*)d_in[22];
    const float* bz2  = (const float*)d_in[23];
    const float* Wh2  = (const float*)d_in[24];
    const float* bh2  = (const float*)d_in[25];
    const float* Wp3  = (const float*)d_in[26];
    const float* bp3  = (const float*)d_in[27];
    const float* W3   = (const float*)d_in[28];
    const float* as3  = (const float*)d_in[29];
    const float* ad3  = (const float*)d_in[30];
    const float* b3   = (const float*)d_in[31];
    const float* Wr3  = (const float*)d_in[32];
    const float* br3  = (const float*)d_in[33];
    const float* Wz3  = (const float*)d_in[34];
    const float* bz3  = (const float*)d_in[35];
    const float* Wh3  = (const float*)d_in[36];
    const float* bh3  = (const float*)d_in[37];

    const int Nn = in_sizes[0] / 128;   // 50000
    const int E  = in_sizes[1] / 2;     // 800000
    const int* srcp = ei;
    const int* dstp = ei + E;

    // ---------------- workspace layout (bf16-state) ----------------
    float* AS  = (float*)d_ws;                          // [N,8]
    float* AD  = AS + (size_t)Nn * 8;                   // [N,8]
    float* H3f = AD + (size_t)Nn * 8;                   // [N,64] fp32 (L3 h_in)
    float* Z3f = H3f + (size_t)Nn * 64;                 // [N,64] fp32 (L3 z)
    unsigned short* X0b  = (unsigned short*)(Z3f + (size_t)Nn * 64); // [N,256]
    unsigned short* XPb  = X0b + (size_t)Nn * 256;      // [N,256]
    unsigned short* Gb   = XPb + (size_t)Nn * 256;      // [N,256]
    unsigned short* RHb  = Gb  + (size_t)Nn * 256;      // [N,256]
    unsigned short* HINb = RHb + (size_t)Nn * 256;      // [N,128]
    unsigned short* Zb   = HINb + (size_t)Nn * 128;     // [N,256]
    unsigned short* wpool = Zb + (size_t)Nn * 256;
    unsigned short* Wtrc   = wpool;                     // 128*256
    unsigned short* W1c    = Wtrc   + 128 * 256;        // 256*256
    unsigned short* Wr1c   = W1c    + 256 * 256;        // 512*256
    unsigned short* Wz1c   = Wr1c   + 512 * 256;
    unsigned short* Wh1c   = Wz1c   + 512 * 256;
    unsigned short* Wp2W2c = Wh1c   + 512 * 256;        // 256*256 combined
    unsigned short* Wr2c   = Wp2W2c + 256 * 256;        // 256*128
    unsigned short* Wz2c   = Wr2c   + 256 * 128;
    unsigned short* Wh2c   = Wz2c   + 256 * 128;
    unsigned short* Wp3W3c = Wh2c   + 256 * 128;        // 128*128 combined
    unsigned short* Wr3c   = Wp3W3c + 128 * 128;        // 128*64
    unsigned short* Wz3c   = Wr3c   + 128 * 64;
    unsigned short* Wh3c   = Wz3c   + 128 * 64;
    int* ioff = (int*)(((size_t)(Wh3c + 128 * 64) + 15) & ~(size_t)15);
    int* cnt  = ioff + (Nn + 1);
    int* cur  = cnt + Nn;
    int* bsum = cur + Nn;                               // [(N+255)/256]
    int* csr  = bsum + ((Nn + 255) / 256 + 8);

    dim3 blk(256);
    const int nb = (Nn + 255) / 256;   // 196

    // ---------- all 15 weight conversions in ONE launch ----------
    {
        WPack p;
        const float* Ws[15]     = {W_tr, W1, Wr1, Wz1, Wh1,
                                   Wp2, W2, Wr2, Wz2, Wh2,
                                   Wp3, W3, Wr3, Wz3, Wh3};
        unsigned short* Wcs[15] = {Wtrc, W1c, Wr1c, Wz1c, Wh1c,
                                   Wp2W2c, Wp2W2c, Wr2c, Wz2c, Wh2c,
                                   Wp3W3c, Wp3W3c, Wr3c, Wz3c, Wh3c};
        int Ks[15]   = {128, 256, 512, 512, 512, 256, 256, 256, 256, 256, 128, 128, 128, 128, 128};
        int MoSs[15] = {256, 256, 256, 256, 256, 128, 128, 128, 128, 128, 64, 64, 64, 64, 64};
        int MoDs[15] = {256, 256, 256, 256, 256, 256, 256, 128, 128, 128, 128, 128, 64, 64, 64};
        int offs[15] = {0, 0, 0, 0, 0, 0, 128, 0, 0, 0, 0, 64, 0, 0, 0};
        for (int i = 0; i < 15; ++i) {
            p.W[i] = Ws[i]; p.Wc[i] = Wcs[i]; p.K[i] = Ks[i];
            p.MoS[i] = MoSs[i]; p.MoD[i] = MoDs[i]; p.off[i] = offs[i];
        }
        convW_all<<<dim3((512 * 256 + 255) / 256, 15), blk, 0, stream>>>(p);
    }

    // ---------- CSR build (parallel scan) ----------
    hipMemsetAsync(cnt, 0, (size_t)Nn * 4, stream);
    count_k<<<(E + 255) / 256, blk, 0, stream>>>(dstp, E, cnt);
    scan1<<<nb, blk, 0, stream>>>(cnt, Nn, ioff, bsum);
    scan2<<<1, blk, 0, stream>>>(bsum, nb, ioff, Nn, E);
    scan3<<<(Nn + 255) / 256, blk, 0, stream>>>(ioff, bsum, cur, Nn);
    scatter_k<<<(E + 255) / 256, blk, 0, stream>>>(srcp, dstp, E, cur, csr);

    // ---------- stage 0: X0b = bf16(x @ W_tr + b_tr) ----------
    unsigned short* xb = Gb;   // Gb free until gather1
    conv_k<<<(int)(((long)Nn * 128 / 4 + 255) / 256), blk, 0, stream>>>(x, xb, (long)Nn * 128);
    gemm_t<128,0><<<gblocks(Nn, 256, 128), blk, 0, stream>>>(
        xb, 128, nullptr, 0, Wtrc, b_tr, nullptr, X0b, nullptr,
        nullptr, nullptr, nullptr, nullptr, Nn, 256);

    // ================= layer 1 (D=256, H=8, C=32) =================
    gemm_t<128,0><<<gblocks(Nn, 256, 128), blk, 0, stream>>>(
        X0b, 256, nullptr, 0, W1c, nullptr, nullptr, XPb, nullptr,
        nullptr, nullptr, nullptr, nullptr, Nn, 256);
    alpha_b<<<(Nn * 8 + 255) / 256, blk, 0, stream>>>(XPb, as1, ad1, AS, AD, Nn, 8, 32);
    launch_gather(ioff, csr, XPb, AS, AD, b1, Gb, Nn, 8, 32, 1, stream);
    gemm_rz<0><<<gblocks(Nn, 256, 64), blk, 0, stream>>>(
        Gb, 256, X0b, 256, Wr1c, Wz1c, br1, bz1, X0b, nullptr, RHb, Zb, nullptr, Nn, 256);
    gemm_t<128,3><<<gblocks(Nn, 256, 128), blk, 0, stream>>>(
        Gb, 256, RHb, 256, Wh1c, bh1, nullptr, XPb, nullptr,
        X0b, Zb, nullptr, nullptr, Nn, 256);
    // XPb holds x1 (bf16)

    // ================= layer 2 (D=128, H=4, C=32) =================
    gemm_t<128,4><<<gblocks(Nn, 256, 128), blk, 0, stream>>>(
        XPb, 256, nullptr, 0, Wp2W2c, bp2, nullptr, HINb, X0b,
        nullptr, nullptr, nullptr, nullptr, Nn, 256);
    alpha_b<<<(Nn * 4 + 255) / 256, blk, 0, stream>>>(X0b, as2, ad2, AS, AD, Nn, 4, 32);
    launch_gather(ioff, csr, X0b, AS, AD, b2, Gb, Nn, 4, 32, 1, stream);
    gemm_rz<0><<<gblocks(Nn, 128, 64), blk, 0, stream>>>(
        Gb, 128, HINb, 128, Wr2c, Wz2c, br2, bz2, HINb, nullptr, RHb, Zb, nullptr, Nn, 128);
    gemm_t<128,3><<<gblocks(Nn, 128, 128), blk, 0, stream>>>(
        Gb, 128, RHb, 128, Wh2c, bh2, nullptr, X0b, nullptr,
        HINb, Zb, nullptr, nullptr, Nn, 128);
    // X0b holds x2 (bf16)

    // ================= layer 3 (D=64, H=1, C=64, fp32 state) =================
    unsigned short* H3b  = HINb;                 // [N,64]
    unsigned short* XP3b = HINb + (size_t)Nn * 64;
    gemm_t<128,4><<<gblocks(Nn, 128, 128), blk, 0, stream>>>(
        X0b, 128, nullptr, 0, Wp3W3c, bp3, H3f, H3b, XP3b,
        nullptr, nullptr, nullptr, nullptr, Nn, 128);
    alpha_b<<<(Nn + 255) / 256, blk, 0, stream>>>(XP3b, as3, ad3, AS, AD, Nn, 1, 64);
    launch_gather(ioff, csr, XP3b, AS, AD, b3, Gb, Nn, 1, 64, 0, stream);
    gemm_rz<1><<<gblocks(Nn, 64, 64), blk, 0, stream>>>(
        Gb, 64, H3b, 64, Wr3c, Wz3c, br3, bz3, nullptr, H3f, RHb, nullptr, Z3f, Nn, 64);
    gemm_t<64,5><<<gblocks(Nn, 64, 64), blk, 0, stream>>>(
        Gb, 64, RHb, 64, Wh3c, bh3, (float*)d_out, nullptr, nullptr,
        nullptr, nullptr, H3f, Z3f, Nn, 64);
}

// Round 14
// 542.834 us; speedup vs baseline: 1.3567x; 1.0573x over previous
//
#include <hip/hip_runtime.h>

#define NEG_SLOPE 0.2f

typedef __attribute__((ext_vector_type(8))) short short8;
typedef __attribute__((ext_vector_type(8))) unsigned short ushort8;
typedef __attribute__((ext_vector_type(4))) float f32x4;

__device__ __forceinline__ unsigned short f2bf(float f) {
    unsigned int u = __float_as_uint(f);
    u += 0x7fff + ((u >> 16) & 1);     // round-to-nearest-even
    return (unsigned short)(u >> 16);
}
__device__ __forceinline__ float bf2f(unsigned short s) {
    return __uint_as_float(((unsigned int)s) << 16);
}

// async global->LDS, 16B per lane; lds base must be wave-uniform
__device__ __forceinline__ void gll16(const void* g, void* l) {
    __builtin_amdgcn_global_load_lds(
        (const __attribute__((address_space(1))) void*)g,
        (__attribute__((address_space(3))) void*)l, 16, 0, 0);
}

// ---------------- converters ----------------
__global__ void conv_k(const float* __restrict__ in, unsigned short* __restrict__ out, long n)
{
    long i = ((long)blockIdx.x * blockDim.x + threadIdx.x) * 4;
    if (i >= n) return;
    float4 f = *(const float4*)&in[i];
    ushort4 o; o.x = f2bf(f.x); o.y = f2bf(f.y); o.z = f2bf(f.z); o.w = f2bf(f.w);
    *(ushort4*)&out[i] = o;
}

// all 15 weights in one launch; supports column-offset packing into wider dst:
// Wc[((k>>3)*MoD + off + m)*8 + (k&7)] = bf16(W[k*MoS + m])
struct WPack {
    const float* W[15];
    unsigned short* Wc[15];
    int K[15];
    int MoS[15];
    int MoD[15];
    int off[15];
};
__global__ void convW_all(WPack p)
{
    int wi = blockIdx.y;
    int i = blockIdx.x * blockDim.x + threadIdx.x;
    int K = p.K[wi], MoS = p.MoS[wi];
    if (i >= K * MoS) return;
    int k = i / MoS, m = i % MoS;
    p.Wc[wi][((long)(k >> 3) * p.MoD[wi] + p.off[wi] + m) * 8 + (k & 7)] = f2bf(p.W[wi][i]);
}

// XCD-grouping remap (bijective with pad): consecutive work items share an XCD L2.
__device__ __forceinline__ int xcd_work(int TOT) {
    int L = blockIdx.x;
    int per = (TOT + 7) >> 3;
    int wk = (L & 7) * per + (L >> 3);
    return (wk < TOT) ? wk : -1;
}

// ================= bf16 MFMA GEMM: BM=64, BK=64, 4 waves (2x2) =================
// MODE 0: outF/outB = acc+bias (either may be null)
// MODE 3: o = (1-z)*hin + z*tanh(acc+bias), z/hin bf16; outB   (GRU finish, L1/L2)
// MODE 4: split projection: col<Mo/2 -> outF/outB = acc+bias[col]; col>=Mo/2 -> outB2
// MODE 5: o = (1-Zf)*HinF + Zf*tanh(acc+bias); outF fp32        (GRU finish, L3)
template<int BN, int MODE>
__global__ __launch_bounds__(256) void gemm_t(
    const unsigned short* __restrict__ U, int K1,
    const unsigned short* __restrict__ V, int K2,
    const unsigned short* __restrict__ Wc, const float* __restrict__ bias,
    float* __restrict__ outF, unsigned short* __restrict__ outB,
    unsigned short* __restrict__ outB2,
    const unsigned short* __restrict__ HinB, const unsigned short* __restrict__ Zb,
    const float* __restrict__ HinF, const float* __restrict__ Zf,
    int rows, int Mo)
{
    constexpr int NIF = BN / 32;       // frags per wave in N (WC=2)
    __shared__ __align__(16) unsigned short As[8][64][8];    // 8KB
    __shared__ __align__(16) unsigned short Bs[8][BN][8];    // 16KB / 8KB
    const int CB = Mo / BN;
    const int RB = (rows + 63) >> 6;
    int wk = xcd_work(CB * RB);
    if (wk < 0) return;
    const int col0 = (wk % CB) * BN;
    const int row0 = (wk / CB) * 64;
    const int K = K1 + K2;
    const int tid = threadIdx.x;
    const int l = tid & 63, w = tid >> 6;
    const int lm = l & 15, lg = l >> 4;
    const int wrow = (w >> 1) * 32;
    const int wcol = (w & 1) * (BN / 2);
    f32x4 acc[2][NIF] = {};

    for (int k0 = 0; k0 < K; k0 += 64) {
#pragma unroll
        for (int i = 0; i < 2; ++i) {
            int c = i * 256 + tid;
            int m = c & 63, g = c >> 6;           // g wave-uniform
            int row = row0 + m; if (row >= rows) row = rows - 1;
            int k = k0 + g * 8;
            const unsigned short* sp = (k < K1) ? U + (long)row * K1 + k
                                                : V + (long)row * K2 + (k - K1);
            gll16(sp, &As[0][0][0] + ((i * 256 + w * 64) << 3));
        }
#pragma unroll
        for (int j = 0; j < NIF; ++j) {
            int c = j * 256 + tid;
            int n = c & (BN - 1), g = c / BN;     // g wave-uniform
            gll16(Wc + ((long)((k0 >> 3) + g) * Mo + (col0 + n)) * 8,
                  &Bs[0][0][0] + ((j * 256 + w * 64) << 3));
        }
        __syncthreads();
#pragma unroll
        for (int kk = 0; kk < 2; ++kk) {
            short8 a[2], b[NIF];
#pragma unroll
            for (int mi = 0; mi < 2; ++mi)
                a[mi] = *(const short8*)&As[kk * 4 + lg][wrow + mi * 16 + lm][0];
#pragma unroll
            for (int ni = 0; ni < NIF; ++ni)
                b[ni] = *(const short8*)&Bs[kk * 4 + lg][wcol + ni * 16 + lm][0];
#pragma unroll
            for (int mi = 0; mi < 2; ++mi)
#pragma unroll
                for (int ni = 0; ni < NIF; ++ni)
                    acc[mi][ni] = __builtin_amdgcn_mfma_f32_16x16x32_bf16(a[mi], b[ni], acc[mi][ni], 0, 0, 0);
        }
        __syncthreads();
    }

    const int halfMo = Mo >> 1;
#pragma unroll
    for (int mi = 0; mi < 2; ++mi) {
        int rbase = row0 + wrow + mi * 16 + lg * 4;
#pragma unroll
        for (int r = 0; r < 4; ++r) {
            int row = rbase + r;
            if (row >= rows) continue;
#pragma unroll
            for (int ni = 0; ni < NIF; ++ni) {
                int col = col0 + wcol + ni * 16 + lm;
                float v = acc[mi][ni][r];
                if (MODE == 0) {
                    v += (bias ? bias[col] : 0.f);
                    long idx = (long)row * Mo + col;
                    if (outF) outF[idx] = v;
                    if (outB) outB[idx] = f2bf(v);
                } else if (MODE == 3) {
                    v += bias[col];
                    long idx = (long)row * Mo + col;
                    float z = bf2f(Zb[idx]);
                    float o = (1.f - z) * bf2f(HinB[idx]) + z * tanhf(v);
                    outB[idx] = f2bf(o);
                } else if (MODE == 5) {
                    v += bias[col];
                    long idx = (long)row * Mo + col;
                    float z = Zf[idx];
                    float o = (1.f - z) * HinF[idx] + z * tanhf(v);
                    outF[idx] = o;
                } else {  // MODE 4
                    if (col < halfMo) {
                        v += bias[col];
                        long idx = (long)row * halfMo + col;
                        if (outF) outF[idx] = v;
                        outB[idx] = f2bf(v);
                    } else {
                        outB2[(long)row * halfMo + (col - halfMo)] = f2bf(v);
                    }
                }
            }
        }
    }
}

// ================= fused r+z dual-B GEMM: BM=64, BN=64, shared A =================
template<int FP>
__global__ __launch_bounds__(256) void gemm_rz(
    const unsigned short* __restrict__ U, int K1,
    const unsigned short* __restrict__ V, int K2,
    const unsigned short* __restrict__ Wrc, const unsigned short* __restrict__ Wzc,
    const float* __restrict__ br, const float* __restrict__ bz,
    const unsigned short* __restrict__ HinB, const float* __restrict__ HinF,
    unsigned short* __restrict__ RHb,
    unsigned short* __restrict__ ZoutB, float* __restrict__ ZoutF,
    int rows, int Mo)
{
    __shared__ __align__(16) unsigned short As[8][64][8];   // 8KB
    __shared__ __align__(16) unsigned short Br[8][64][8];   // 8KB
    __shared__ __align__(16) unsigned short Bz[8][64][8];   // 8KB
    const int CB = Mo >> 6;
    const int RB = (rows + 63) >> 6;
    int wk = xcd_work(CB * RB);
    if (wk < 0) return;
    const int col0 = (wk % CB) * 64;
    const int row0 = (wk / CB) * 64;
    const int K = K1 + K2;
    const int tid = threadIdx.x;
    const int l = tid & 63, w = tid >> 6;
    const int lm = l & 15, lg = l >> 4;
    const int wrow = (w >> 1) * 32;
    const int wcol = (w & 1) * 32;
    f32x4 accr[2][2] = {}, accz[2][2] = {};

    for (int k0 = 0; k0 < K; k0 += 64) {
#pragma unroll
        for (int i = 0; i < 2; ++i) {
            int c = i * 256 + tid;
            int m = c & 63, g = c >> 6;
            int row = row0 + m; if (row >= rows) row = rows - 1;
            int k = k0 + g * 8;
            const unsigned short* sp = (k < K1) ? U + (long)row * K1 + k
                                                : V + (long)row * K2 + (k - K1);
            gll16(sp, &As[0][0][0] + ((i * 256 + w * 64) << 3));
        }
#pragma unroll
        for (int j = 0; j < 2; ++j) {
            int c = j * 256 + tid;
            int n = c & 63, g = c >> 6;
            long base = ((long)((k0 >> 3) + g) * Mo + (col0 + n)) * 8;
            gll16(Wrc + base, &Br[0][0][0] + ((j * 256 + w * 64) << 3));
            gll16(Wzc + base, &Bz[0][0][0] + ((j * 256 + w * 64) << 3));
        }
        __syncthreads();
#pragma unroll
        for (int kk = 0; kk < 2; ++kk) {
            short8 a[2], brv[2], bzv[2];
#pragma unroll
            for (int mi = 0; mi < 2; ++mi)
                a[mi] = *(const short8*)&As[kk * 4 + lg][wrow + mi * 16 + lm][0];
#pragma unroll
            for (int ni = 0; ni < 2; ++ni) {
                brv[ni] = *(const short8*)&Br[kk * 4 + lg][wcol + ni * 16 + lm][0];
                bzv[ni] = *(const short8*)&Bz[kk * 4 + lg][wcol + ni * 16 + lm][0];
            }
#pragma unroll
            for (int mi = 0; mi < 2; ++mi)
#pragma unroll
                for (int ni = 0; ni < 2; ++ni) {
                    accr[mi][ni] = __builtin_amdgcn_mfma_f32_16x16x32_bf16(a[mi], brv[ni], accr[mi][ni], 0, 0, 0);
                    accz[mi][ni] = __builtin_amdgcn_mfma_f32_16x16x32_bf16(a[mi], bzv[ni], accz[mi][ni], 0, 0, 0);
                }
        }
        __syncthreads();
    }

#pragma unroll
    for (int mi = 0; mi < 2; ++mi) {
        int rbase = row0 + wrow + mi * 16 + lg * 4;
#pragma unroll
        for (int r = 0; r < 4; ++r) {
            int row = rbase + r;
            if (row >= rows) continue;
#pragma unroll
            for (int ni = 0; ni < 2; ++ni) {
                int col = col0 + wcol + ni * 16 + lm;
                long idx = (long)row * Mo + col;
                float rv = 1.f / (1.f + __expf(-(accr[mi][ni][r] + br[col])));
                float zv = 1.f / (1.f + __expf(-(accz[mi][ni][r] + bz[col])));
                float hin = FP ? HinF[idx] : bf2f(HinB[idx]);
                RHb[idx] = f2bf(rv * hin);
                if (FP) ZoutF[idx] = zv;
                else    ZoutB[idx] = f2bf(zv);
            }
        }
    }
}

// ---------------- alpha (bf16 input, vectorized) ----------------
__global__ void alpha_b(const unsigned short* __restrict__ XPb,
                        const float* __restrict__ a_s, const float* __restrict__ a_d,
                        float* __restrict__ AS, float* __restrict__ AD,
                        int Nn, int H, int C)
{
    int i = blockIdx.x * blockDim.x + threadIdx.x;
    if (i >= Nn * H) return;
    int n = i / H, h = i % H;
    const unsigned short* xp = &XPb[(long)n * H * C + (long)h * C];
    const float* asv = &a_s[h * C];
    const float* adv = &a_d[h * C];
    float ss = 0.f, sd = 0.f;
    for (int c = 0; c < C; c += 8) {
        ushort8 xv = *(const ushort8*)&xp[c];
#pragma unroll
        for (int q = 0; q < 8; ++q) {
            float v = bf2f(xv[q]);
            ss += v * asv[c + q];
            sd += v * adv[c + q];
        }
    }
    AS[i] = ss; AD[i] = sd;
}

// ---------------- CSR build: parallel 3-phase scan ----------------
__global__ void count_k(const int* __restrict__ dst, int E, int* __restrict__ cnt)
{
    int e = blockIdx.x * blockDim.x + threadIdx.x;
    if (e < E) atomicAdd(&cnt[dst[e]], 1);
}

__global__ __launch_bounds__(256) void scan1(const int* __restrict__ cnt, int Nn,
                                             int* __restrict__ off, int* __restrict__ bsum)
{
    __shared__ int tmp[256];
    int gid = blockIdx.x * 256 + threadIdx.x;
    int v = (gid < Nn) ? cnt[gid] : 0;
    tmp[threadIdx.x] = v;
    __syncthreads();
    for (int d = 1; d < 256; d <<= 1) {
        int t = (threadIdx.x >= (unsigned)d) ? tmp[threadIdx.x - d] : 0;
        __syncthreads();
        tmp[threadIdx.x] += t;
        __syncthreads();
    }
    if (gid < Nn) off[gid] = tmp[threadIdx.x] - v;   // exclusive within block
    if (threadIdx.x == 255) bsum[blockIdx.x] = tmp[255];
}

__global__ __launch_bounds__(256) void scan2(int* __restrict__ bsum, int nb,
                                             int* __restrict__ off, int Nn, int E)
{
    __shared__ int tmp[256];
    int v = (threadIdx.x < (unsigned)nb) ? bsum[threadIdx.x] : 0;
    tmp[threadIdx.x] = v;
    __syncthreads();
    for (int d = 1; d < 256; d <<= 1) {
        int t = (threadIdx.x >= (unsigned)d) ? tmp[threadIdx.x - d] : 0;
        __syncthreads();
        tmp[threadIdx.x] += t;
        __syncthreads();
    }
    if (threadIdx.x < (unsigned)nb) bsum[threadIdx.x] = tmp[threadIdx.x] - v;
    if (threadIdx.x == 0) off[Nn] = E;
}

__global__ void scan3(int* __restrict__ off, const int* __restrict__ bsum,
                      int* __restrict__ cur, int Nn)
{
    int gid = blockIdx.x * blockDim.x + threadIdx.x;
    if (gid < Nn) {
        int o = off[gid] + bsum[gid >> 8];
        off[gid] = o;
        cur[gid] = o;
    }
}

__global__ void scatter_k(const int* __restrict__ src, const int* __restrict__ dst, int E,
                          int* __restrict__ cur, int* __restrict__ csr_src)
{
    int e = blockIdx.x * blockDim.x + threadIdx.x;
    if (e < E) {
        int p = atomicAdd(&cur[dst[e]], 1);
        csr_src[p] = src[e];
    }
}

// ---------------- bf16 GAT gather (8 feats/lane, 4x-unrolled edge loop) ----------------
__global__ void gat_gather_b(const int* __restrict__ off, const int* __restrict__ csr_src,
                             const unsigned short* __restrict__ XPb,
                             const float* __restrict__ AS, const float* __restrict__ AD,
                             const float* __restrict__ bias,
                             unsigned short* __restrict__ Gout,
                             int Nn, int H, int C, int do_elu)
{
    const int D = H * C;
    const int lpn = D >> 3;
    const int npw = 64 / lpn;
    int lane = threadIdx.x & 63;
    long wave = ((long)blockIdx.x * blockDim.x + threadIdx.x) >> 6;
    int sub = lane / lpn;
    int cl = lane % lpn;
    long n = wave * npw + sub;
    if (n >= Nn) return;
    int j = cl * 8;
    int h = j / C;
    float ad = AD[n * H + h];
    float v = AS[n * H + h] + ad;
    v = v > 0.f ? v : NEG_SLOPE * v;
    float w = __expf(v);
    float den = w;
    float acc[8];
    {
        ushort8 xv = *(const ushort8*)&XPb[(long)n * D + j];
#pragma unroll
        for (int q = 0; q < 8; ++q) acc[q] = w * bf2f(xv[q]);
    }
    int b0 = off[n], b1 = off[n + 1];
    int i = b0;
    for (; i + 4 <= b1; i += 4) {
        int s0 = csr_src[i + 0];
        int s1 = csr_src[i + 1];
        int s2 = csr_src[i + 2];
        int s3 = csr_src[i + 3];
        float v0 = AS[s0 * H + h] + ad;
        float v1 = AS[s1 * H + h] + ad;
        float v2 = AS[s2 * H + h] + ad;
        float v3 = AS[s3 * H + h] + ad;
        v0 = v0 > 0.f ? v0 : NEG_SLOPE * v0;
        v1 = v1 > 0.f ? v1 : NEG_SLOPE * v1;
        v2 = v2 > 0.f ? v2 : NEG_SLOPE * v2;
        v3 = v3 > 0.f ? v3 : NEG_SLOPE * v3;
        float w0 = __expf(v0), w1 = __expf(v1), w2 = __expf(v2), w3 = __expf(v3);
        den += (w0 + w1) + (w2 + w3);
        ushort8 x0 = *(const ushort8*)&XPb[(long)s0 * D + j];
        ushort8 x1 = *(const ushort8*)&XPb[(long)s1 * D + j];
        ushort8 x2 = *(const ushort8*)&XPb[(long)s2 * D + j];
        ushort8 x3 = *(const ushort8*)&XPb[(long)s3 * D + j];
#pragma unroll
        for (int q = 0; q < 8; ++q)
            acc[q] += w0 * bf2f(x0[q]) + w1 * bf2f(x1[q]) + w2 * bf2f(x2[q]) + w3 * bf2f(x3[q]);
    }
    for (; i < b1; ++i) {
        int s = csr_src[i];
        v = AS[s * H + h] + ad;
        v = v > 0.f ? v : NEG_SLOPE * v;
        w = __expf(v);
        den += w;
        ushort8 xv = *(const ushort8*)&XPb[(long)s * D + j];
#pragma unroll
        for (int q = 0; q < 8; ++q) acc[q] += w * bf2f(xv[q]);
    }
    float inv = 1.f / (den + 1e-16f);
    ushort8 ov;
#pragma unroll
    for (int q = 0; q < 8; ++q) {
        float o = acc[q] * inv + bias[j + q];
        if (do_elu) o = o > 0.f ? o : expm1f(o);
        ov[q] = f2bf(o);
    }
    *(ushort8*)&Gout[(long)n * D + j] = ov;
}

static inline int pad8(int t) { return ((t + 7) / 8) * 8; }
static inline int gblocks(int rows, int Mo, int BN) {
    return pad8((Mo / BN) * ((rows + 63) >> 6));
}

static inline void launch_gather(const int* ioff, const int* csr,
                                 const unsigned short* xp, const float* AS, const float* AD,
                                 const float* bias, unsigned short* gout,
                                 int Nn, int H, int C, int elu, hipStream_t stream)
{
    int D = H * C;
    int lpn = D >> 3;
    int npw = 64 / lpn;
    long waves = (Nn + npw - 1) / npw;
    int blocks = (int)((waves * 64 + 255) / 256);
    gat_gather_b<<<blocks, 256, 0, stream>>>(ioff, csr, xp, AS, AD, bias, gout, Nn, H, C, elu);
}

extern "C" void kernel_launch(void* const* d_in, const int* in_sizes, int n_in,
                              void* d_out, int out_size, void* d_ws, size_t ws_size,
                              hipStream_t stream)
{
    const float* x    = (const float*)d_in[0];
    const int*   ei   = (const int*)  d_in[1];
    const float* W_tr = (const float*)d_in[2];
    const float* b_tr = (const float*)d_in[3];
    const float* W1   = (const float*)d_in[4];
    const float* as1  = (const float*)d_in[5];
    const float* ad1  = (const float*)d_in[6];
    const float* b1   = (const float*)d_in[7];
    const float* Wr1  = (const float*)d_in[8];
    const float* br1  = (const float*)d_in[9];
    const float* Wz1  = (const float*)d_in[10];
    const float* bz1  = (const float*)d_in[11];
    const float* Wh1  = (const float*)d_in[12];
    const float* bh1  = (const float*)d_in[13];
    const float* Wp2  = (const float*)d_in[14];
    const float* bp2  = (const float*)d_in[15];
    const float* W2   = (const float*)d_in[16];
    const float* as2  = (const float*)d_in[17];
    const float* ad2  = (const float*)d_in[18];
    const float* b2   = (const float*)d_in[19];
    const float* Wr2  = (const float*)d_in[20];
    const float* br2  = (const float*)d_in[21];
    const float* Wz2  = (const float*)d_in[22];
    const float* bz2  = (const float*)d_in[23];
    const float* Wh2  = (const float*)d_in[24];
    const float* bh2  = (const float*)d_in[25];
    const float* Wp3  = (const float*)d_in[26];
    const float* bp3  = (const float*)d_in[27];
    const float* W3   = (const float*)d_in[28];
    const float* as3  = (const float*)d_in[29];
    const float* ad3  = (const float*)d_in[30];
    const float* b3   = (const float*)d_in[31];
    const float* Wr3  = (const float*)d_in[32];
    const float* br3  = (const float*)d_in[33];
    const float* Wz3  = (const float*)d_in[34];
    const float* bz3  = (const float*)d_in[35];
    const float* Wh3  = (const float*)d_in[36];
    const float* bh3  = (const float*)d_in[37];

    const int Nn = in_sizes[0] / 128;   // 50000
    const int E  = in_sizes[1] / 2;     // 800000
    const int* srcp = ei;
    const int* dstp = ei + E;

    // ---------------- workspace layout (bf16-state) ----------------
    float* AS  = (float*)d_ws;                          // [N,8]
    float* AD  = AS + (size_t)Nn * 8;                   // [N,8]
    float* H3f = AD + (size_t)Nn * 8;                   // [N,64] fp32 (L3 h_in)
    float* Z3f = H3f + (size_t)Nn * 64;                 // [N,64] fp32 (L3 z)
    unsigned short* X0b  = (unsigned short*)(Z3f + (size_t)Nn * 64); // [N,256]
    unsigned short* XPb  = X0b + (size_t)Nn * 256;      // [N,256]
    unsigned short* Gb   = XPb + (size_t)Nn * 256;      // [N,256]
    unsigned short* RHb  = Gb  + (size_t)Nn * 256;      // [N,256]
    unsigned short* HINb = RHb + (size_t)Nn * 256;      // [N,128]
    unsigned short* Zb   = HINb + (size_t)Nn * 128;     // [N,256]
    unsigned short* wpool = Zb + (size_t)Nn * 256;
    unsigned short* Wtrc   = wpool;                     // 128*256
    unsigned short* W1c    = Wtrc   + 128 * 256;        // 256*256
    unsigned short* Wr1c   = W1c    + 256 * 256;        // 512*256
    unsigned short* Wz1c   = Wr1c   + 512 * 256;
    unsigned short* Wh1c   = Wz1c   + 512 * 256;
    unsigned short* Wp2W2c = Wh1c   + 512 * 256;        // 256*256 combined
    unsigned short* Wr2c   = Wp2W2c + 256 * 256;        // 256*128
    unsigned short* Wz2c   = Wr2c   + 256 * 128;
    unsigned short* Wh2c   = Wz2c   + 256 * 128;
    unsigned short* Wp3W3c = Wh2c   + 256 * 128;        // 128*128 combined
    unsigned short* Wr3c   = Wp3W3c + 128 * 128;        // 128*64
    unsigned short* Wz3c   = Wr3c   + 128 * 64;
    unsigned short* Wh3c   = Wz3c   + 128 * 64;
    int* ioff = (int*)(((size_t)(Wh3c + 128 * 64) + 15) & ~(size_t)15);
    int* cnt  = ioff + (Nn + 1);
    int* cur  = cnt + Nn;
    int* bsum = cur + Nn;                               // [(N+255)/256]
    int* csr  = bsum + ((Nn + 255) / 256 + 8);

    dim3 blk(256);
    const int nb = (Nn + 255) / 256;   // 196

    // ---------- all 15 weight conversions in ONE launch ----------
    {
        WPack p;
        const float* Ws[15]     = {W_tr, W1, Wr1, Wz1, Wh1,
                                   Wp2, W2, Wr2, Wz2, Wh2,
                                   Wp3, W3, Wr3, Wz3, Wh3};
        unsigned short* Wcs[15] = {Wtrc, W1c, Wr1c, Wz1c, Wh1c,
                                   Wp2W2c, Wp2W2c, Wr2c, Wz2c, Wh2c,
                                   Wp3W3c, Wp3W3c, Wr3c, Wz3c, Wh3c};
        int Ks[15]   = {128, 256, 512, 512, 512, 256, 256, 256, 256, 256, 128, 128, 128, 128, 128};
        int MoSs[15] = {256, 256, 256, 256, 256, 128, 128, 128, 128, 128, 64, 64, 64, 64, 64};
        int MoDs[15] = {256, 256, 256, 256, 256, 256, 256, 128, 128, 128, 128, 128, 64, 64, 64};
        int offs[15] = {0, 0, 0, 0, 0, 0, 128, 0, 0, 0, 0, 64, 0, 0, 0};
        for (int i = 0; i < 15; ++i) {
            p.W[i] = Ws[i]; p.Wc[i] = Wcs[i]; p.K[i] = Ks[i];
            p.MoS[i] = MoSs[i]; p.MoD[i] = MoDs[i]; p.off[i] = offs[i];
        }
        convW_all<<<dim3((512 * 256 + 255) / 256, 15), blk, 0, stream>>>(p);
    }

    // ---------- CSR build (parallel scan) ----------
    hipMemsetAsync(cnt, 0, (size_t)Nn * 4, stream);
    count_k<<<(E + 255) / 256, blk, 0, stream>>>(dstp, E, cnt);
    scan1<<<nb, blk, 0, stream>>>(cnt, Nn, ioff, bsum);
    scan2<<<1, blk, 0, stream>>>(bsum, nb, ioff, Nn, E);
    scan3<<<(Nn + 255) / 256, blk, 0, stream>>>(ioff, bsum, cur, Nn);
    scatter_k<<<(E + 255) / 256, blk, 0, stream>>>(srcp, dstp, E, cur, csr);

    // ---------- stage 0: X0b = bf16(x @ W_tr + b_tr) ----------
    unsigned short* xb = Gb;   // Gb free until gather1
    conv_k<<<(int)(((long)Nn * 128 / 4 + 255) / 256), blk, 0, stream>>>(x, xb, (long)Nn * 128);
    gemm_t<128,0><<<gblocks(Nn, 256, 128), blk, 0, stream>>>(
        xb, 128, nullptr, 0, Wtrc, b_tr, nullptr, X0b, nullptr,
        nullptr, nullptr, nullptr, nullptr, Nn, 256);

    // ================= layer 1 (D=256, H=8, C=32) =================
    gemm_t<128,0><<<gblocks(Nn, 256, 128), blk, 0, stream>>>(
        X0b, 256, nullptr, 0, W1c, nullptr, nullptr, XPb, nullptr,
        nullptr, nullptr, nullptr, nullptr, Nn, 256);
    alpha_b<<<(Nn * 8 + 255) / 256, blk, 0, stream>>>(XPb, as1, ad1, AS, AD, Nn, 8, 32);
    launch_gather(ioff, csr, XPb, AS, AD, b1, Gb, Nn, 8, 32, 1, stream);
    gemm_rz<0><<<gblocks(Nn, 256, 64), blk, 0, stream>>>(
        Gb, 256, X0b, 256, Wr1c, Wz1c, br1, bz1, X0b, nullptr, RHb, Zb, nullptr, Nn, 256);
    gemm_t<128,3><<<gblocks(Nn, 256, 128), blk, 0, stream>>>(
        Gb, 256, RHb, 256, Wh1c, bh1, nullptr, XPb, nullptr,
        X0b, Zb, nullptr, nullptr, Nn, 256);
    // XPb holds x1 (bf16)

    // ================= layer 2 (D=128, H=4, C=32) =================
    gemm_t<128,4><<<gblocks(Nn, 256, 128), blk, 0, stream>>>(
        XPb, 256, nullptr, 0, Wp2W2c, bp2, nullptr, HINb, X0b,
        nullptr, nullptr, nullptr, nullptr, Nn, 256);
    alpha_b<<<(Nn * 4 + 255) / 256, blk, 0, stream>>>(X0b, as2, ad2, AS, AD, Nn, 4, 32);
    launch_gather(ioff, csr, X0b, AS, AD, b2, Gb, Nn, 4, 32, 1, stream);
    gemm_rz<0><<<gblocks(Nn, 128, 64), blk, 0, stream>>>(
        Gb, 128, HINb, 128, Wr2c, Wz2c, br2, bz2, HINb, nullptr, RHb, Zb, nullptr, Nn, 128);
    gemm_t<128,3><<<gblocks(Nn, 128, 128), blk, 0, stream>>>(
        Gb, 128, RHb, 128, Wh2c, bh2, nullptr, X0b, nullptr,
        HINb, Zb, nullptr, nullptr, Nn, 128);
    // X0b holds x2 (bf16)

    // ================= layer 3 (D=64, H=1, C=64, fp32 state) =================
    unsigned short* H3b  = HINb;                 // [N,64]
    unsigned short* XP3b = HINb + (size_t)Nn * 64;
    gemm_t<128,4><<<gblocks(Nn, 128, 128), blk, 0, stream>>>(
        X0b, 128, nullptr, 0, Wp3W3c, bp3, H3f, H3b, XP3b,
        nullptr, nullptr, nullptr, nullptr, Nn, 128);
    alpha_b<<<(Nn + 255) / 256, blk, 0, stream>>>(XP3b, as3, ad3, AS, AD, Nn, 1, 64);
    launch_gather(ioff, csr, XP3b, AS, AD, b3, Gb, Nn, 1, 64, 0, stream);
    gemm_rz<1><<<gblocks(Nn, 64, 64), blk, 0, stream>>>(
        Gb, 64, H3b, 64, Wr3c, Wz3c, br3, bz3, nullptr, H3f, RHb, nullptr, Z3f, Nn, 64);
    gemm_t<64,5><<<gblocks(Nn, 64, 64), blk, 0, stream>>>(
        Gb, 64, RHb, 64, Wh3c, bh3, (float*)d_out, nullptr, nullptr,
        nullptr, nullptr, H3f, Z3f, Nn, 64);
}

// Round 15
// 542.647 us; speedup vs baseline: 1.3572x; 1.0003x over previous
//
#include <hip/hip_runtime.h>

#define NEG_SLOPE 0.2f

typedef __attribute__((ext_vector_type(8))) short short8;
typedef __attribute__((ext_vector_type(8))) unsigned short ushort8;
typedef __attribute__((ext_vector_type(4))) float f32x4;

__device__ __forceinline__ unsigned short f2bf(float f) {
    unsigned int u = __float_as_uint(f);
    u += 0x7fff + ((u >> 16) & 1);     // round-to-nearest-even
    return (unsigned short)(u >> 16);
}
__device__ __forceinline__ float bf2f(unsigned short s) {
    return __uint_as_float(((unsigned int)s) << 16);
}

// async global->LDS, 16B per lane; lds base must be wave-uniform
__device__ __forceinline__ void gll16(const void* g, void* l) {
    __builtin_amdgcn_global_load_lds(
        (const __attribute__((address_space(1))) void*)g,
        (__attribute__((address_space(3))) void*)l, 16, 0, 0);
}

// ---------------- converters ----------------
__global__ void conv_k(const float* __restrict__ in, unsigned short* __restrict__ out, long n)
{
    long i = ((long)blockIdx.x * blockDim.x + threadIdx.x) * 4;
    if (i >= n) return;
    float4 f = *(const float4*)&in[i];
    ushort4 o; o.x = f2bf(f.x); o.y = f2bf(f.y); o.z = f2bf(f.z); o.w = f2bf(f.w);
    *(ushort4*)&out[i] = o;
}

// all 15 weights in one launch; supports column-offset packing into wider dst:
// Wc[((k>>3)*MoD + off + m)*8 + (k&7)] = bf16(W[k*MoS + m])
struct WPack {
    const float* W[15];
    unsigned short* Wc[15];
    int K[15];
    int MoS[15];
    int MoD[15];
    int off[15];
};
__global__ void convW_all(WPack p)
{
    int wi = blockIdx.y;
    int i = blockIdx.x * blockDim.x + threadIdx.x;
    int K = p.K[wi], MoS = p.MoS[wi];
    if (i >= K * MoS) return;
    int k = i / MoS, m = i % MoS;
    p.Wc[wi][((long)(k >> 3) * p.MoD[wi] + p.off[wi] + m) * 8 + (k & 7)] = f2bf(p.W[wi][i]);
}

// XCD-grouping remap (bijective with pad): consecutive work items share an XCD L2.
__device__ __forceinline__ int xcd_work(int TOT) {
    int L = blockIdx.x;
    int per = (TOT + 7) >> 3;
    int wk = (L & 7) * per + (L >> 3);
    return (wk < TOT) ? wk : -1;
}

// ================= bf16 MFMA GEMM: BM=64, BK=64, 4 waves (2x2) =================
// MODE 0: outF/outB = acc+bias (either may be null)
// MODE 3: o = (1-z)*hin + z*tanh(acc+bias), z/hin bf16; outB   (GRU finish, L1/L2)
// MODE 4: split projection: col<Mo/2 -> outF/outB = acc+bias[col]; col>=Mo/2 -> outB2
// MODE 5: o = (1-Zf)*HinF + Zf*tanh(acc+bias); outF fp32        (GRU finish, L3)
template<int BN, int MODE>
__global__ __launch_bounds__(256) void gemm_t(
    const unsigned short* __restrict__ U, int K1,
    const unsigned short* __restrict__ V, int K2,
    const unsigned short* __restrict__ Wc, const float* __restrict__ bias,
    float* __restrict__ outF, unsigned short* __restrict__ outB,
    unsigned short* __restrict__ outB2,
    const unsigned short* __restrict__ HinB, const unsigned short* __restrict__ Zb,
    const float* __restrict__ HinF, const float* __restrict__ Zf,
    int rows, int Mo)
{
    constexpr int NIF = BN / 32;       // frags per wave in N (WC=2)
    __shared__ __align__(16) unsigned short As[8][64][8];    // 8KB
    __shared__ __align__(16) unsigned short Bs[8][BN][8];    // 16KB / 8KB
    const int CB = Mo / BN;
    const int RB = (rows + 63) >> 6;
    int wk = xcd_work(CB * RB);
    if (wk < 0) return;
    const int col0 = (wk % CB) * BN;
    const int row0 = (wk / CB) * 64;
    const int K = K1 + K2;
    const int tid = threadIdx.x;
    const int l = tid & 63, w = tid >> 6;
    const int lm = l & 15, lg = l >> 4;
    const int wrow = (w >> 1) * 32;
    const int wcol = (w & 1) * (BN / 2);
    f32x4 acc[2][NIF] = {};

    for (int k0 = 0; k0 < K; k0 += 64) {
#pragma unroll
        for (int i = 0; i < 2; ++i) {
            int c = i * 256 + tid;
            int m = c & 63, g = c >> 6;           // g wave-uniform
            int row = row0 + m; if (row >= rows) row = rows - 1;
            int k = k0 + g * 8;
            const unsigned short* sp = (k < K1) ? U + (long)row * K1 + k
                                                : V + (long)row * K2 + (k - K1);
            gll16(sp, &As[0][0][0] + ((i * 256 + w * 64) << 3));
        }
#pragma unroll
        for (int j = 0; j < NIF; ++j) {
            int c = j * 256 + tid;
            int n = c & (BN - 1), g = c / BN;     // g wave-uniform
            gll16(Wc + ((long)((k0 >> 3) + g) * Mo + (col0 + n)) * 8,
                  &Bs[0][0][0] + ((j * 256 + w * 64) << 3));
        }
        __syncthreads();
#pragma unroll
        for (int kk = 0; kk < 2; ++kk) {
            short8 a[2], b[NIF];
#pragma unroll
            for (int mi = 0; mi < 2; ++mi)
                a[mi] = *(const short8*)&As[kk * 4 + lg][wrow + mi * 16 + lm][0];
#pragma unroll
            for (int ni = 0; ni < NIF; ++ni)
                b[ni] = *(const short8*)&Bs[kk * 4 + lg][wcol + ni * 16 + lm][0];
#pragma unroll
            for (int mi = 0; mi < 2; ++mi)
#pragma unroll
                for (int ni = 0; ni < NIF; ++ni)
                    acc[mi][ni] = __builtin_amdgcn_mfma_f32_16x16x32_bf16(a[mi], b[ni], acc[mi][ni], 0, 0, 0);
        }
        __syncthreads();
    }

    const int halfMo = Mo >> 1;
#pragma unroll
    for (int mi = 0; mi < 2; ++mi) {
        int rbase = row0 + wrow + mi * 16 + lg * 4;
#pragma unroll
        for (int r = 0; r < 4; ++r) {
            int row = rbase + r;
            if (row >= rows) continue;
#pragma unroll
            for (int ni = 0; ni < NIF; ++ni) {
                int col = col0 + wcol + ni * 16 + lm;
                float v = acc[mi][ni][r];
                if (MODE == 0) {
                    v += (bias ? bias[col] : 0.f);
                    long idx = (long)row * Mo + col;
                    if (outF) outF[idx] = v;
                    if (outB) outB[idx] = f2bf(v);
                } else if (MODE == 3) {
                    v += bias[col];
                    long idx = (long)row * Mo + col;
                    float z = bf2f(Zb[idx]);
                    float o = (1.f - z) * bf2f(HinB[idx]) + z * tanhf(v);
                    outB[idx] = f2bf(o);
                } else if (MODE == 5) {
                    v += bias[col];
                    long idx = (long)row * Mo + col;
                    float z = Zf[idx];
                    float o = (1.f - z) * HinF[idx] + z * tanhf(v);
                    outF[idx] = o;
                } else {  // MODE 4
                    if (col < halfMo) {
                        v += bias[col];
                        long idx = (long)row * halfMo + col;
                        if (outF) outF[idx] = v;
                        outB[idx] = f2bf(v);
                    } else {
                        outB2[(long)row * halfMo + (col - halfMo)] = f2bf(v);
                    }
                }
            }
        }
    }
}

// ================= fused r+z dual-B GEMM: BM=64, BN templated, shared A =========
// FP=0: hin/z bf16; FP=1: hin/z fp32.
//   RHb = bf16( sigmoid(acc_r + br) * hin ),  Zout = sigmoid(acc_z + bz)
template<int BN, int FP>
__global__ __launch_bounds__(256) void gemm_rz(
    const unsigned short* __restrict__ U, int K1,
    const unsigned short* __restrict__ V, int K2,
    const unsigned short* __restrict__ Wrc, const unsigned short* __restrict__ Wzc,
    const float* __restrict__ br, const float* __restrict__ bz,
    const unsigned short* __restrict__ HinB, const float* __restrict__ HinF,
    unsigned short* __restrict__ RHb,
    unsigned short* __restrict__ ZoutB, float* __restrict__ ZoutF,
    int rows, int Mo)
{
    constexpr int NIF = BN / 32;
    __shared__ __align__(16) unsigned short As[8][64][8];   // 8KB
    __shared__ __align__(16) unsigned short Br[8][BN][8];   // 8/16KB
    __shared__ __align__(16) unsigned short Bz[8][BN][8];   // 8/16KB
    const int CB = Mo / BN;
    const int RB = (rows + 63) >> 6;
    int wk = xcd_work(CB * RB);
    if (wk < 0) return;
    const int col0 = (wk % CB) * BN;
    const int row0 = (wk / CB) * 64;
    const int K = K1 + K2;
    const int tid = threadIdx.x;
    const int l = tid & 63, w = tid >> 6;
    const int lm = l & 15, lg = l >> 4;
    const int wrow = (w >> 1) * 32;
    const int wcol = (w & 1) * (BN / 2);
    f32x4 accr[2][NIF] = {}, accz[2][NIF] = {};

    for (int k0 = 0; k0 < K; k0 += 64) {
#pragma unroll
        for (int i = 0; i < 2; ++i) {
            int c = i * 256 + tid;
            int m = c & 63, g = c >> 6;
            int row = row0 + m; if (row >= rows) row = rows - 1;
            int k = k0 + g * 8;
            const unsigned short* sp = (k < K1) ? U + (long)row * K1 + k
                                                : V + (long)row * K2 + (k - K1);
            gll16(sp, &As[0][0][0] + ((i * 256 + w * 64) << 3));
        }
#pragma unroll
        for (int j = 0; j < NIF; ++j) {
            int c = j * 256 + tid;
            int n = c & (BN - 1), g = c / BN;
            long base = ((long)((k0 >> 3) + g) * Mo + (col0 + n)) * 8;
            gll16(Wrc + base, &Br[0][0][0] + ((j * 256 + w * 64) << 3));
            gll16(Wzc + base, &Bz[0][0][0] + ((j * 256 + w * 64) << 3));
        }
        __syncthreads();
#pragma unroll
        for (int kk = 0; kk < 2; ++kk) {
            short8 a[2], brv[NIF], bzv[NIF];
#pragma unroll
            for (int mi = 0; mi < 2; ++mi)
                a[mi] = *(const short8*)&As[kk * 4 + lg][wrow + mi * 16 + lm][0];
#pragma unroll
            for (int ni = 0; ni < NIF; ++ni) {
                brv[ni] = *(const short8*)&Br[kk * 4 + lg][wcol + ni * 16 + lm][0];
                bzv[ni] = *(const short8*)&Bz[kk * 4 + lg][wcol + ni * 16 + lm][0];
            }
#pragma unroll
            for (int mi = 0; mi < 2; ++mi)
#pragma unroll
                for (int ni = 0; ni < NIF; ++ni) {
                    accr[mi][ni] = __builtin_amdgcn_mfma_f32_16x16x32_bf16(a[mi], brv[ni], accr[mi][ni], 0, 0, 0);
                    accz[mi][ni] = __builtin_amdgcn_mfma_f32_16x16x32_bf16(a[mi], bzv[ni], accz[mi][ni], 0, 0, 0);
                }
        }
        __syncthreads();
    }

#pragma unroll
    for (int mi = 0; mi < 2; ++mi) {
        int rbase = row0 + wrow + mi * 16 + lg * 4;
#pragma unroll
        for (int r = 0; r < 4; ++r) {
            int row = rbase + r;
            if (row >= rows) continue;
#pragma unroll
            for (int ni = 0; ni < NIF; ++ni) {
                int col = col0 + wcol + ni * 16 + lm;
                long idx = (long)row * Mo + col;
                float rv = 1.f / (1.f + __expf(-(accr[mi][ni][r] + br[col])));
                float zv = 1.f / (1.f + __expf(-(accz[mi][ni][r] + bz[col])));
                float hin = FP ? HinF[idx] : bf2f(HinB[idx]);
                RHb[idx] = f2bf(rv * hin);
                if (FP) ZoutF[idx] = zv;
                else    ZoutB[idx] = f2bf(zv);
            }
        }
    }
}

// ---------------- alpha (bf16 input, vectorized) ----------------
__global__ void alpha_b(const unsigned short* __restrict__ XPb,
                        const float* __restrict__ a_s, const float* __restrict__ a_d,
                        float* __restrict__ AS, float* __restrict__ AD,
                        int Nn, int H, int C)
{
    int i = blockIdx.x * blockDim.x + threadIdx.x;
    if (i >= Nn * H) return;
    int n = i / H, h = i % H;
    const unsigned short* xp = &XPb[(long)n * H * C + (long)h * C];
    const float* asv = &a_s[h * C];
    const float* adv = &a_d[h * C];
    float ss = 0.f, sd = 0.f;
    for (int c = 0; c < C; c += 8) {
        ushort8 xv = *(const ushort8*)&xp[c];
#pragma unroll
        for (int q = 0; q < 8; ++q) {
            float v = bf2f(xv[q]);
            ss += v * asv[c + q];
            sd += v * adv[c + q];
        }
    }
    AS[i] = ss; AD[i] = sd;
}

// ---------------- CSR build: parallel 3-phase scan ----------------
__global__ void count_k(const int* __restrict__ dst, int E, int* __restrict__ cnt)
{
    int e = blockIdx.x * blockDim.x + threadIdx.x;
    if (e < E) atomicAdd(&cnt[dst[e]], 1);
}

__global__ __launch_bounds__(256) void scan1(const int* __restrict__ cnt, int Nn,
                                             int* __restrict__ off, int* __restrict__ bsum)
{
    __shared__ int tmp[256];
    int gid = blockIdx.x * 256 + threadIdx.x;
    int v = (gid < Nn) ? cnt[gid] : 0;
    tmp[threadIdx.x] = v;
    __syncthreads();
    for (int d = 1; d < 256; d <<= 1) {
        int t = (threadIdx.x >= (unsigned)d) ? tmp[threadIdx.x - d] : 0;
        __syncthreads();
        tmp[threadIdx.x] += t;
        __syncthreads();
    }
    if (gid < Nn) off[gid] = tmp[threadIdx.x] - v;   // exclusive within block
    if (threadIdx.x == 255) bsum[blockIdx.x] = tmp[255];
}

__global__ __launch_bounds__(256) void scan2(int* __restrict__ bsum, int nb,
                                             int* __restrict__ off, int Nn, int E)
{
    __shared__ int tmp[256];
    int v = (threadIdx.x < (unsigned)nb) ? bsum[threadIdx.x] : 0;
    tmp[threadIdx.x] = v;
    __syncthreads();
    for (int d = 1; d < 256; d <<= 1) {
        int t = (threadIdx.x >= (unsigned)d) ? tmp[threadIdx.x - d] : 0;
        __syncthreads();
        tmp[threadIdx.x] += t;
        __syncthreads();
    }
    if (threadIdx.x < (unsigned)nb) bsum[threadIdx.x] = tmp[threadIdx.x] - v;
    if (threadIdx.x == 0) off[Nn] = E;
}

__global__ void scan3(int* __restrict__ off, const int* __restrict__ bsum,
                      int* __restrict__ cur, int Nn)
{
    int gid = blockIdx.x * blockDim.x + threadIdx.x;
    if (gid < Nn) {
        int o = off[gid] + bsum[gid >> 8];
        off[gid] = o;
        cur[gid] = o;
    }
}

__global__ void scatter_k(const int* __restrict__ src, const int* __restrict__ dst, int E,
                          int* __restrict__ cur, int* __restrict__ csr_src)
{
    int e = blockIdx.x * blockDim.x + threadIdx.x;
    if (e < E) {
        int p = atomicAdd(&cur[dst[e]], 1);
        csr_src[p] = src[e];
    }
}

// ---------------- bf16 GAT gather (8 feats/lane, 4x-unrolled edge loop) ----------------
__global__ void gat_gather_b(const int* __restrict__ off, const int* __restrict__ csr_src,
                             const unsigned short* __restrict__ XPb,
                             const float* __restrict__ AS, const float* __restrict__ AD,
                             const float* __restrict__ bias,
                             unsigned short* __restrict__ Gout,
                             int Nn, int H, int C, int do_elu)
{
    const int D = H * C;
    const int lpn = D >> 3;
    const int npw = 64 / lpn;
    int lane = threadIdx.x & 63;
    long wave = ((long)blockIdx.x * blockDim.x + threadIdx.x) >> 6;
    int sub = lane / lpn;
    int cl = lane % lpn;
    long n = wave * npw + sub;
    if (n >= Nn) return;
    int j = cl * 8;
    int h = j / C;
    float ad = AD[n * H + h];
    float v = AS[n * H + h] + ad;
    v = v > 0.f ? v : NEG_SLOPE * v;
    float w = __expf(v);
    float den = w;
    float acc[8];
    {
        ushort8 xv = *(const ushort8*)&XPb[(long)n * D + j];
#pragma unroll
        for (int q = 0; q < 8; ++q) acc[q] = w * bf2f(xv[q]);
    }
    int b0 = off[n], b1 = off[n + 1];
    int i = b0;
    for (; i + 4 <= b1; i += 4) {
        int s0 = csr_src[i + 0];
        int s1 = csr_src[i + 1];
        int s2 = csr_src[i + 2];
        int s3 = csr_src[i + 3];
        float v0 = AS[s0 * H + h] + ad;
        float v1 = AS[s1 * H + h] + ad;
        float v2 = AS[s2 * H + h] + ad;
        float v3 = AS[s3 * H + h] + ad;
        v0 = v0 > 0.f ? v0 : NEG_SLOPE * v0;
        v1 = v1 > 0.f ? v1 : NEG_SLOPE * v1;
        v2 = v2 > 0.f ? v2 : NEG_SLOPE * v2;
        v3 = v3 > 0.f ? v3 : NEG_SLOPE * v3;
        float w0 = __expf(v0), w1 = __expf(v1), w2 = __expf(v2), w3 = __expf(v3);
        den += (w0 + w1) + (w2 + w3);
        ushort8 x0 = *(const ushort8*)&XPb[(long)s0 * D + j];
        ushort8 x1 = *(const ushort8*)&XPb[(long)s1 * D + j];
        ushort8 x2 = *(const ushort8*)&XPb[(long)s2 * D + j];
        ushort8 x3 = *(const ushort8*)&XPb[(long)s3 * D + j];
#pragma unroll
        for (int q = 0; q < 8; ++q)
            acc[q] += w0 * bf2f(x0[q]) + w1 * bf2f(x1[q]) + w2 * bf2f(x2[q]) + w3 * bf2f(x3[q]);
    }
    for (; i < b1; ++i) {
        int s = csr_src[i];
        v = AS[s * H + h] + ad;
        v = v > 0.f ? v : NEG_SLOPE * v;
        w = __expf(v);
        den += w;
        ushort8 xv = *(const ushort8*)&XPb[(long)s * D + j];
#pragma unroll
        for (int q = 0; q < 8; ++q) acc[q] += w * bf2f(xv[q]);
    }
    float inv = 1.f / (den + 1e-16f);
    ushort8 ov;
#pragma unroll
    for (int q = 0; q < 8; ++q) {
        float o = acc[q] * inv + bias[j + q];
        if (do_elu) o = o > 0.f ? o : expm1f(o);
        ov[q] = f2bf(o);
    }
    *(ushort8*)&Gout[(long)n * D + j] = ov;
}

static inline int pad8(int t) { return ((t + 7) / 8) * 8; }
static inline int gblocks(int rows, int Mo, int BN) {
    return pad8((Mo / BN) * ((rows + 63) >> 6));
}

static inline void launch_gather(const int* ioff, const int* csr,
                                 const unsigned short* xp, const float* AS, const float* AD,
                                 const float* bias, unsigned short* gout,
                                 int Nn, int H, int C, int elu, hipStream_t stream)
{
    int D = H * C;
    int lpn = D >> 3;
    int npw = 64 / lpn;
    long waves = (Nn + npw - 1) / npw;
    int blocks = (int)((waves * 64 + 255) / 256);
    gat_gather_b<<<blocks, 256, 0, stream>>>(ioff, csr, xp, AS, AD, bias, gout, Nn, H, C, elu);
}

extern "C" void kernel_launch(void* const* d_in, const int* in_sizes, int n_in,
                              void* d_out, int out_size, void* d_ws, size_t ws_size,
                              hipStream_t stream)
{
    const float* x    = (const float*)d_in[0];
    const int*   ei   = (const int*)  d_in[1];
    const float* W_tr = (const float*)d_in[2];
    const float* b_tr = (const float*)d_in[3];
    const float* W1   = (const float*)d_in[4];
    const float* as1  = (const float*)d_in[5];
    const float* ad1  = (const float*)d_in[6];
    const float* b1   = (const float*)d_in[7];
    const float* Wr1  = (const float*)d_in[8];
    const float* br1  = (const float*)d_in[9];
    const float* Wz1  = (const float*)d_in[10];
    const float* bz1  = (const float*)d_in[11];
    const float* Wh1  = (const float*)d_in[12];
    const float* bh1  = (const float*)d_in[13];
    const float* Wp2  = (const float*)d_in[14];
    const float* bp2  = (const float*)d_in[15];
    const float* W2   = (const float*)d_in[16];
    const float* as2  = (const float*)d_in[17];
    const float* ad2  = (const float*)d_in[18];
    const float* b2   = (const float*)d_in[19];
    const float* Wr2  = (const float*)d_in[20];
    const float* br2  = (const float*)d_in[21];
    const float* Wz2  = (const float*)d_in[22];
    const float* bz2  = (const float*)d_in[23];
    const float* Wh2  = (const float*)d_in[24];
    const float* bh2  = (const float*)d_in[25];
    const float* Wp3  = (const float*)d_in[26];
    const float* bp3  = (const float*)d_in[27];
    const float* W3   = (const float*)d_in[28];
    const float* as3  = (const float*)d_in[29];
    const float* ad3  = (const float*)d_in[30];
    const float* b3   = (const float*)d_in[31];
    const float* Wr3  = (const float*)d_in[32];
    const float* br3  = (const float*)d_in[33];
    const float* Wz3  = (const float*)d_in[34];
    const float* bz3  = (const float*)d_in[35];
    const float* Wh3  = (const float*)d_in[36];
    const float* bh3  = (const float*)d_in[37];

    const int Nn = in_sizes[0] / 128;   // 50000
    const int E  = in_sizes[1] / 2;     // 800000
    const int* srcp = ei;
    const int* dstp = ei + E;

    // ---------------- workspace layout (bf16-state) ----------------
    float* AS  = (float*)d_ws;                          // [N,8]
    float* AD  = AS + (size_t)Nn * 8;                   // [N,8]
    float* H3f = AD + (size_t)Nn * 8;                   // [N,64] fp32 (L3 h_in)
    float* Z3f = H3f + (size_t)Nn * 64;                 // [N,64] fp32 (L3 z)
    unsigned short* X0b  = (unsigned short*)(Z3f + (size_t)Nn * 64); // [N,256]
    unsigned short* XPb  = X0b + (size_t)Nn * 256;      // [N,256]
    unsigned short* Gb   = XPb + (size_t)Nn * 256;      // [N,256]
    unsigned short* RHb  = Gb  + (size_t)Nn * 256;      // [N,256]
    unsigned short* HINb = RHb + (size_t)Nn * 256;      // [N,128]
    unsigned short* Zb   = HINb + (size_t)Nn * 128;     // [N,256]
    unsigned short* wpool = Zb + (size_t)Nn * 256;
    unsigned short* Wtrc   = wpool;                     // 128*256
    unsigned short* W1c    = Wtrc   + 128 * 256;        // 256*256
    unsigned short* Wr1c   = W1c    + 256 * 256;        // 512*256
    unsigned short* Wz1c   = Wr1c   + 512 * 256;
    unsigned short* Wh1c   = Wz1c   + 512 * 256;
    unsigned short* Wp2W2c = Wh1c   + 512 * 256;        // 256*256 combined
    unsigned short* Wr2c   = Wp2W2c + 256 * 256;        // 256*128
    unsigned short* Wz2c   = Wr2c   + 256 * 128;
    unsigned short* Wh2c   = Wz2c   + 256 * 128;
    unsigned short* Wp3W3c = Wh2c   + 256 * 128;        // 128*128 combined
    unsigned short* Wr3c   = Wp3W3c + 128 * 128;        // 128*64
    unsigned short* Wz3c   = Wr3c   + 128 * 64;
    unsigned short* Wh3c   = Wz3c   + 128 * 64;
    int* ioff = (int*)(((size_t)(Wh3c + 128 * 64) + 15) & ~(size_t)15);
    int* cnt  = ioff + (Nn + 1);
    int* cur  = cnt + Nn;
    int* bsum = cur + Nn;                               // [(N+255)/256]
    int* csr  = bsum + ((Nn + 255) / 256 + 8);

    dim3 blk(256);
    const int nb = (Nn + 255) / 256;   // 196

    // ---------- all 15 weight conversions in ONE launch ----------
    {
        WPack p;
        const float* Ws[15]     = {W_tr, W1, Wr1, Wz1, Wh1,
                                   Wp2, W2, Wr2, Wz2, Wh2,
                                   Wp3, W3, Wr3, Wz3, Wh3};
        unsigned short* Wcs[15] = {Wtrc, W1c, Wr1c, Wz1c, Wh1c,
                                   Wp2W2c, Wp2W2c, Wr2c, Wz2c, Wh2c,
                                   Wp3W3c, Wp3W3c, Wr3c, Wz3c, Wh3c};
        int Ks[15]   = {128, 256, 512, 512, 512, 256, 256, 256, 256, 256, 128, 128, 128, 128, 128};
        int MoSs[15] = {256, 256, 256, 256, 256, 128, 128, 128, 128, 128, 64, 64, 64, 64, 64};
        int MoDs[15] = {256, 256, 256, 256, 256, 256, 256, 128, 128, 128, 128, 128, 64, 64, 64};
        int offs[15] = {0, 0, 0, 0, 0, 0, 128, 0, 0, 0, 0, 64, 0, 0, 0};
        for (int i = 0; i < 15; ++i) {
            p.W[i] = Ws[i]; p.Wc[i] = Wcs[i]; p.K[i] = Ks[i];
            p.MoS[i] = MoSs[i]; p.MoD[i] = MoDs[i]; p.off[i] = offs[i];
        }
        convW_all<<<dim3((512 * 256 + 255) / 256, 15), blk, 0, stream>>>(p);
    }

    // ---------- CSR build (parallel scan) ----------
    hipMemsetAsync(cnt, 0, (size_t)Nn * 4, stream);
    count_k<<<(E + 255) / 256, blk, 0, stream>>>(dstp, E, cnt);
    scan1<<<nb, blk, 0, stream>>>(cnt, Nn, ioff, bsum);
    scan2<<<1, blk, 0, stream>>>(bsum, nb, ioff, Nn, E);
    scan3<<<(Nn + 255) / 256, blk, 0, stream>>>(ioff, bsum, cur, Nn);
    scatter_k<<<(E + 255) / 256, blk, 0, stream>>>(srcp, dstp, E, cur, csr);

    // ---------- stage 0: X0b = bf16(x @ W_tr + b_tr) ----------
    unsigned short* xb = Gb;   // Gb free until gather1
    conv_k<<<(int)(((long)Nn * 128 / 4 + 255) / 256), blk, 0, stream>>>(x, xb, (long)Nn * 128);
    gemm_t<128,0><<<gblocks(Nn, 256, 128), blk, 0, stream>>>(
        xb, 128, nullptr, 0, Wtrc, b_tr, nullptr, X0b, nullptr,
        nullptr, nullptr, nullptr, nullptr, Nn, 256);

    // ================= layer 1 (D=256, H=8, C=32) =================
    gemm_t<128,0><<<gblocks(Nn, 256, 128), blk, 0, stream>>>(
        X0b, 256, nullptr, 0, W1c, nullptr, nullptr, XPb, nullptr,
        nullptr, nullptr, nullptr, nullptr, Nn, 256);
    alpha_b<<<(Nn * 8 + 255) / 256, blk, 0, stream>>>(XPb, as1, ad1, AS, AD, Nn, 8, 32);
    launch_gather(ioff, csr, XPb, AS, AD, b1, Gb, Nn, 8, 32, 1, stream);
    gemm_rz<128,0><<<gblocks(Nn, 256, 128), blk, 0, stream>>>(
        Gb, 256, X0b, 256, Wr1c, Wz1c, br1, bz1, X0b, nullptr, RHb, Zb, nullptr, Nn, 256);
    gemm_t<128,3><<<gblocks(Nn, 256, 128), blk, 0, stream>>>(
        Gb, 256, RHb, 256, Wh1c, bh1, nullptr, XPb, nullptr,
        X0b, Zb, nullptr, nullptr, Nn, 256);
    // XPb holds x1 (bf16)

    // ================= layer 2 (D=128, H=4, C=32) =================
    gemm_t<128,4><<<gblocks(Nn, 256, 128), blk, 0, stream>>>(
        XPb, 256, nullptr, 0, Wp2W2c, bp2, nullptr, HINb, X0b,
        nullptr, nullptr, nullptr, nullptr, Nn, 256);
    alpha_b<<<(Nn * 4 + 255) / 256, blk, 0, stream>>>(X0b, as2, ad2, AS, AD, Nn, 4, 32);
    launch_gather(ioff, csr, X0b, AS, AD, b2, Gb, Nn, 4, 32, 1, stream);
    gemm_rz<64,0><<<gblocks(Nn, 128, 64), blk, 0, stream>>>(
        Gb, 128, HINb, 128, Wr2c, Wz2c, br2, bz2, HINb, nullptr, RHb, Zb, nullptr, Nn, 128);
    gemm_t<128,3><<<gblocks(Nn, 128, 128), blk, 0, stream>>>(
        Gb, 128, RHb, 128, Wh2c, bh2, nullptr, X0b, nullptr,
        HINb, Zb, nullptr, nullptr, Nn, 128);
    // X0b holds x2 (bf16)

    // ================= layer 3 (D=64, H=1, C=64, fp32 state) =================
    unsigned short* H3b  = HINb;                 // [N,64]
    unsigned short* XP3b = HINb + (size_t)Nn * 64;
    gemm_t<128,4><<<gblocks(Nn, 128, 128), blk, 0, stream>>>(
        X0b, 128, nullptr, 0, Wp3W3c, bp3, H3f, H3b, XP3b,
        nullptr, nullptr, nullptr, nullptr, Nn, 128);
    alpha_b<<<(Nn + 255) / 256, blk, 0, stream>>>(XP3b, as3, ad3, AS, AD, Nn, 1, 64);
    launch_gather(ioff, csr, XP3b, AS, AD, b3, Gb, Nn, 1, 64, 0, stream);
    gemm_rz<64,1><<<gblocks(Nn, 64, 64), blk, 0, stream>>>(
        Gb, 64, H3b, 64, Wr3c, Wz3c, br3, bz3, nullptr, H3f, RHb, nullptr, Z3f, Nn, 64);
    gemm_t<64,5><<<gblocks(Nn, 64, 64), blk, 0, stream>>>(
        Gb, 64, RHb, 64, Wh3c, bh3, (float*)d_out, nullptr, nullptr,
        nullptr, nullptr, H3f, Z3f, Nn, 64);
}